// Round 12
// baseline (536.214 us; speedup 1.0000x reference)
//
#include <hip/hip_runtime.h>
#include <hip/hip_bf16.h>
#include <math.h>

// Problem constants
#define B_   2
#define N_   8192
#define DM   768
#define NH   12
#define HD   64

// Workspace layout:
//   Qh (f16) at byte 0           : 12,582,912 f16  (= floats [0, 6291456))
//   Ql (f16) after it            : 12,582,912 f16
//   (OLNh/OLNl bf16 reuse Qh/Ql region after attention)
//   AC  at float 12,582,912, SUMS at float 19,922,944
//   W splits (589824 u16 x2) live in the AC region while it is dead.
#define QL_ELEM_OFF 12582912ull
#define AC_OFF      12582912ull
#define SUMS_OFF    19922944ull
#define W_ELEMS     589824

typedef short bf16x8 __attribute__((ext_vector_type(8)));
typedef _Float16 f16x8 __attribute__((ext_vector_type(8)));
typedef _Float16 f16x4 __attribute__((ext_vector_type(4)));
typedef float f32x4  __attribute__((ext_vector_type(4)));
typedef unsigned short u16x8 __attribute__((ext_vector_type(8)));
typedef unsigned short u16x4 __attribute__((ext_vector_type(4)));

__device__ __forceinline__ size_t ac_base(int grp) {
    return 8388608ull - (8388608ull >> grp);
}

__device__ __forceinline__ unsigned short f2bf(float f) {
    __hip_bfloat16 h = __float2bfloat16(f);
    return __builtin_bit_cast(unsigned short, h);
}
__device__ __forceinline__ float bf2f(unsigned short u) {
    __hip_bfloat16 h = __builtin_bit_cast(__hip_bfloat16, u);
    return __bfloat162float(h);
}
// fp16 RNE split: f ~= hi + lo with |f - hi - lo| <= 2^-22 |f|.
// NOTE (R6 lesson): the hi/lo split is REQUIRED on Q/K, P, and V -- the
// downstream renorm (x / x.sum over ~8192 positions) has cancellation in the
// denominator and amplifies per-element errors by up to ~3e4; dropping any
// lo term (fp16-only, 2^-11) blew absmax to 6.5 vs the 0.1 threshold.
__device__ __forceinline__ void split2h(float f, _Float16& h, _Float16& l) {
    h = (_Float16)f;
    l = (_Float16)(f - (float)h);
}

// XOR-chunk swizzle for 2-byte arrays, pitch 64 elements (128 B row).
// 16B chunks XORed by (row&7): b128 frag reads conflict-free.
#define SW(row, col) ((((row) << 6)) + ((((col) >> 3) ^ ((row) & 7)) << 3) + ((col) & 7))
// V^T variant: also XOR (row>>3). Validated R4/R7: conflict floor 3.67e6
// with this staging (vs 3.3e7 without).
#define SWV(row, col) ((((row) << 6)) + ((((col) >> 3) ^ ((row) & 7) ^ (((row) >> 3) & 7)) << 3) + ((col) & 7))

// ---------------------------------------------------------------------------
// One-shot fp32 -> bf16 hi/lo split for a 768x768 weight matrix.
// ---------------------------------------------------------------------------
__global__ __launch_bounds__(256) void split_w_kernel(
    const float* __restrict__ src, unsigned short* __restrict__ dh,
    unsigned short* __restrict__ dl) {
    const int i = (blockIdx.x * 256 + threadIdx.x) * 4;
    const float4 v = *(const float4*)(src + i);
    const float vv[4] = {v.x, v.y, v.z, v.w};
    u16x4 h, l;
#pragma unroll
    for (int j = 0; j < 4; ++j) {
        h[j] = f2bf(vv[j]);
        l[j] = f2bf(vv[j] - bf2f(h[j]));
    }
    *(u16x4*)(dh + i) = h;
    *(u16x4*)(dl + i) = l;
}

// ---------------------------------------------------------------------------
// Split-bf16 MFMA GEMM (NT). W is ALWAYS pre-split bf16 (WH/WL). A is fp32
// (Af != nullptr, converted in staging -- GEMM1) or pre-split bf16 (Ah/Al --
// GEMM5, staging is a pure copy). If Ch != nullptr the epilogue writes an
// fp16 RNE hi/lo split; else fp32 to C.
// ---------------------------------------------------------------------------
__global__ __launch_bounds__(256) void gemm_mfma_pre(
    const float* __restrict__ Af,
    const unsigned short* __restrict__ Ah, const unsigned short* __restrict__ Al,
    const unsigned short* __restrict__ WH, const unsigned short* __restrict__ WL,
    const float* __restrict__ bias, float* __restrict__ C,
    _Float16* __restrict__ Ch, _Float16* __restrict__ Cl) {
    __shared__ unsigned short AsH[128][40];
    __shared__ unsigned short AsL[128][40];
    __shared__ unsigned short WsH[128][40];
    __shared__ unsigned short WsL[128][40];

    const int t    = threadIdx.x;
    const int lane = t & 63;
    const int wv   = t >> 6;
    const int c    = lane & 15, q = lane >> 4;
    const int mw   = (wv & 1) * 64, nw = (wv >> 1) * 64;
    const int m0   = blockIdx.x * 128, n0 = blockIdx.y * 128;

    const int srow = t >> 1;
    const int scol = (t & 1) * 16;
    const float* ap = Af ? Af + (size_t)(m0 + srow) * DM + scol : nullptr;
    const unsigned short* ahp = Ah ? Ah + (size_t)(m0 + srow) * DM + scol : nullptr;
    const unsigned short* alp = Al ? Al + (size_t)(m0 + srow) * DM + scol : nullptr;
    const unsigned short* whp = WH + (size_t)(n0 + srow) * DM + scol;
    const unsigned short* wlp = WL + (size_t)(n0 + srow) * DM + scol;

    f32x4 acc[4][4];
#pragma unroll
    for (int mi = 0; mi < 4; ++mi)
#pragma unroll
        for (int ni = 0; ni < 4; ++ni) {
            acc[mi][ni][0] = 0.f; acc[mi][ni][1] = 0.f;
            acc[mi][ni][2] = 0.f; acc[mi][ni][3] = 0.f;
        }

    for (int k0 = 0; k0 < DM; k0 += 32) {
        u16x8 wh0 = *(const u16x8*)(whp + k0);
        u16x8 wh1 = *(const u16x8*)(whp + k0 + 8);
        u16x8 wl0 = *(const u16x8*)(wlp + k0);
        u16x8 wl1 = *(const u16x8*)(wlp + k0 + 8);
        float av[16];
        u16x8 ah0, ah1, al0, al1;
        if (Af) {
            *(float4*)&av[0]  = *(const float4*)(ap + k0);
            *(float4*)&av[4]  = *(const float4*)(ap + k0 + 4);
            *(float4*)&av[8]  = *(const float4*)(ap + k0 + 8);
            *(float4*)&av[12] = *(const float4*)(ap + k0 + 12);
        } else {
            ah0 = *(const u16x8*)(ahp + k0);
            ah1 = *(const u16x8*)(ahp + k0 + 8);
            al0 = *(const u16x8*)(alp + k0);
            al1 = *(const u16x8*)(alp + k0 + 8);
        }
        __syncthreads();
        if (Af) {
#pragma unroll
            for (int i = 0; i < 16; ++i) {
                const float x = av[i];
                const unsigned short xh = f2bf(x);
                AsH[srow][scol + i] = xh;
                AsL[srow][scol + i] = f2bf(x - bf2f(xh));
            }
        } else {
            *(u16x8*)&AsH[srow][scol]     = ah0;
            *(u16x8*)&AsH[srow][scol + 8] = ah1;
            *(u16x8*)&AsL[srow][scol]     = al0;
            *(u16x8*)&AsL[srow][scol + 8] = al1;
        }
        *(u16x8*)&WsH[srow][scol]     = wh0;
        *(u16x8*)&WsH[srow][scol + 8] = wh1;
        *(u16x8*)&WsL[srow][scol]     = wl0;
        *(u16x8*)&WsL[srow][scol + 8] = wl1;
        __syncthreads();

        bf16x8 ah[4], al[4], bh[4], bl[4];
#pragma unroll
        for (int i = 0; i < 4; ++i) {
            ah[i] = *(const bf16x8*)&AsH[mw + i*16 + c][q*8];
            al[i] = *(const bf16x8*)&AsL[mw + i*16 + c][q*8];
            bh[i] = *(const bf16x8*)&WsH[nw + i*16 + c][q*8];
            bl[i] = *(const bf16x8*)&WsL[nw + i*16 + c][q*8];
        }
#pragma unroll
        for (int mi = 0; mi < 4; ++mi)
#pragma unroll
            for (int ni = 0; ni < 4; ++ni) {
                f32x4 v = acc[mi][ni];
                v = __builtin_amdgcn_mfma_f32_16x16x32_bf16(ah[mi], bl[ni], v, 0, 0, 0);
                v = __builtin_amdgcn_mfma_f32_16x16x32_bf16(al[mi], bh[ni], v, 0, 0, 0);
                v = __builtin_amdgcn_mfma_f32_16x16x32_bf16(ah[mi], bh[ni], v, 0, 0, 0);
                acc[mi][ni] = v;
            }
    }

#pragma unroll
    for (int ni = 0; ni < 4; ++ni) {
        const int col = n0 + nw + ni*16 + c;
        const float bv = bias[col];
#pragma unroll
        for (int mi = 0; mi < 4; ++mi)
#pragma unroll
            for (int r = 0; r < 4; ++r) {
                const int row = m0 + mw + mi*16 + q*4 + r;
                const float val = acc[mi][ni][r] + bv;
                if (Ch) {
                    _Float16 hh, ll;
                    split2h(val, hh, ll);
                    Ch[(size_t)row * DM + col] = hh;
                    Cl[(size_t)row * DM + col] = ll;
                } else {
                    C[(size_t)row * DM + col] = val;
                }
            }
    }
}

// ---------------------------------------------------------------------------
// Split-FP16 MFMA flash attention, S^T orientation, 128-query blocks.
// EXACT R7 loop structure (best proven: 242.9-245.8 us, frozen: R10 proved
// not HBM-bound; R8/R9 proved 3 blocks/CU spills). R12 adds FUSED position
// sums in the epilogue: part = sum over this wave's 32 q-rows of o*inv
// (exactly the AC values), butterfly-reduced over the 16 c-lanes, then lane
// c==0 atomicAdds 16 statically-indexed values -- removes the sum_kernel's
// full 29 MB AC re-read. Summation order differs from sum_kernel (fp32
// reassociation only; tolerance headroom 3.2x).
// ---------------------------------------------------------------------------
__global__ __launch_bounds__(256, 2) void attn_mfma_kernel(
    const _Float16* __restrict__ Qh, const _Float16* __restrict__ Ql,
    float* __restrict__ AC, float* __restrict__ SUMS) {
    __shared__ __align__(16) _Float16 KH[4096],  KL[4096];   // K row-major [key][d]
    __shared__ __align__(16) _Float16 VTH[4096], VTL[4096];  // K transposed [d][key]
    __shared__ __align__(16) _Float16 PTH[8192], PTL[8192];  // P^T as [q(128)][k(64)]

    const int t    = threadIdx.x;
    const int lane = t & 63;
    const int w    = t >> 6;
    const int c    = lane & 15, quad = lane >> 4;

    // block -> (grp, b, seg, head, q-tile)
    const int bi  = blockIdx.x;
    const int qt  = bi & 15;           // 16 tiles of 128 queries per 2048
    const int bsh = bi >> 4;
    int grp, local;
    if (bsh < 32)      { grp = 0; local = bsh; }
    else if (bsh < 48) { grp = 1; local = bsh - 32; }
    else               { grp = 2; local = bsh - 48; }
    const int nseg = 4 >> grp;
    const int sseg = 2048 << grp;
    const int r    = 1 << grp;
    const int b    = local / (nseg * 4);
    const int rem  = local - b * nseg * 4;
    const int seg  = rem >> 2;
    const int hg   = rem & 3;
    const int head = grp * 4 + hg;

    const size_t row0 = (size_t)(b * N_ + seg * sseg + grp);
    const int hoff = head * HD;

    const int r0 = (t >> 4) * 4;   // staging rows (keys) 0..60
    const int c0 = (t & 15) * 4;   // staging cols (d)    0..60

    // ---- Q B-frags (loop-invariant): queries qt*128 + w*32 + jt*16 + c ----
    f16x8 qfh[2][2], qfl[2][2];   // [jt][kc]
#pragma unroll
    for (int jt = 0; jt < 2; ++jt) {
        const int qrow = qt*128 + w*32 + jt*16 + c;
        const size_t qoff = (row0 + (size_t)qrow * r) * DM + hoff;
#pragma unroll
        for (int kc = 0; kc < 2; ++kc) {
            f16x8 h = *(const f16x8*)(Qh + qoff + kc*32 + quad*8);
            f16x8 l = *(const f16x8*)(Ql + qoff + kc*32 + quad*8);
            qfh[jt][kc] = h * (_Float16)0.125f;   // fold 1/sqrt(64), exact pow2
            qfl[jt][kc] = l * (_Float16)0.125f;
        }
    }

    // ---- stage K-tile 0 ----
    {
        f16x4 hh[4], ll[4];
#pragma unroll
        for (int i = 0; i < 4; ++i) {
            const size_t off = (row0 + (size_t)(r0 + i) * r) * DM + hoff + c0;
            hh[i] = *(const f16x4*)(Qh + off);
            ll[i] = *(const f16x4*)(Ql + off);
        }
#pragma unroll
        for (int i = 0; i < 4; ++i) {
            *(f16x4*)&KH[SW(r0 + i, c0)] = hh[i];
            *(f16x4*)&KL[SW(r0 + i, c0)] = ll[i];
        }
#pragma unroll
        for (int j = 0; j < 4; ++j) {
            *(f16x4*)&VTH[SWV(c0 + j, r0)] = (f16x4){hh[0][j], hh[1][j], hh[2][j], hh[3][j]};
            *(f16x4*)&VTL[SWV(c0 + j, r0)] = (f16x4){ll[0][j], ll[1][j], ll[2][j], ll[3][j]};
        }
    }
    __syncthreads();

    float m_st[2] = {-1e30f, -1e30f};
    float l_st[2] = {0.f, 0.f};
    f32x4 o[2][4];
#pragma unroll
    for (int jt = 0; jt < 2; ++jt)
#pragma unroll
        for (int i = 0; i < 4; ++i) {
            o[jt][i][0] = 0.f; o[jt][i][1] = 0.f;
            o[jt][i][2] = 0.f; o[jt][i][3] = 0.f;
        }

    for (int kt = 0; kt < 32; ++kt) {
        // prefetch next K-tile into registers
        f16x4 nh[4], nl[4];
        if (kt < 31) {
#pragma unroll
            for (int i = 0; i < 4; ++i) {
                const size_t off = (row0 + (size_t)((kt+1)*64 + r0 + i) * r) * DM + hoff + c0;
                nh[i] = *(const f16x4*)(Qh + off);
                nl[i] = *(const f16x4*)(Ql + off);
            }
        }

        // ---- S^T[k][q]: A = K rows (shared across jt), B = Q^T ----
        f32x4 s[2][4];
#pragma unroll
        for (int jt = 0; jt < 2; ++jt)
#pragma unroll
            for (int mt = 0; mt < 4; ++mt) {
                s[jt][mt][0] = 0.f; s[jt][mt][1] = 0.f;
                s[jt][mt][2] = 0.f; s[jt][mt][3] = 0.f;
            }
#pragma unroll
        for (int kc = 0; kc < 2; ++kc)
#pragma unroll
            for (int mt = 0; mt < 4; ++mt) {
                f16x8 ah = *(const f16x8*)&KH[SW(mt*16 + c, kc*32 + quad*8)];
                f16x8 al = *(const f16x8*)&KL[SW(mt*16 + c, kc*32 + quad*8)];
#pragma unroll
                for (int jt = 0; jt < 2; ++jt) {
                    f32x4 v = s[jt][mt];
                    v = __builtin_amdgcn_mfma_f32_16x16x32_f16(ah, qfl[jt][kc], v, 0, 0, 0);
                    v = __builtin_amdgcn_mfma_f32_16x16x32_f16(al, qfh[jt][kc], v, 0, 0, 0);
                    v = __builtin_amdgcn_mfma_f32_16x16x32_f16(ah, qfh[jt][kc], v, 0, 0, 0);
                    s[jt][mt] = v;
                }
            }

        // ---- per-lane online softmax (independent per jt) + P^T write ----
#pragma unroll
        for (int jt = 0; jt < 2; ++jt) {
            float mloc = s[jt][0][0];
#pragma unroll
            for (int mt = 0; mt < 4; ++mt)
#pragma unroll
                for (int rg = 0; rg < 4; ++rg) mloc = fmaxf(mloc, s[jt][mt][rg]);
            mloc = fmaxf(mloc, __shfl_xor(mloc, 16));
            mloc = fmaxf(mloc, __shfl_xor(mloc, 32));
            // wave-uniform skip: when no query's max moved, alpha == 1 exactly
            if (!__all(mloc <= m_st[jt])) {
                const float mnew  = fmaxf(m_st[jt], mloc);
                const float alpha = __expf(m_st[jt] - mnew);
                m_st[jt] = mnew;
                l_st[jt] *= alpha;
#pragma unroll
                for (int mtd = 0; mtd < 4; ++mtd) {
                    o[jt][mtd][0] *= alpha; o[jt][mtd][1] *= alpha;
                    o[jt][mtd][2] *= alpha; o[jt][mtd][3] *= alpha;
                }
            }
            const float mcur = m_st[jt];
            float psum = 0.f;
            const int prow = w*32 + jt*16 + c;
#pragma unroll
            for (int mt = 0; mt < 4; ++mt) {
                f16x4 hh, ll;
#pragma unroll
                for (int rg = 0; rg < 4; ++rg) {
                    const float pv = __expf(s[jt][mt][rg] - mcur);
                    psum += pv;
                    _Float16 th, tl;
                    split2h(pv, th, tl);
                    hh[rg] = th;
                    ll[rg] = tl;
                }
                *(f16x4*)&PTH[SW(prow, mt*16 + quad*4)] = hh;
                *(f16x4*)&PTL[SW(prow, mt*16 + quad*4)] = ll;
            }
            psum += __shfl_xor(psum, 16);
            psum += __shfl_xor(psum, 32);
            l_st[jt] += psum;
        }
        // wave-private P^T rows: same-wave write->read, no barrier needed

        // ---- PV: O^T[d][q] += V^T P^T (V^T frags shared across jt) ----
#pragma unroll
        for (int kc = 0; kc < 2; ++kc) {
            f16x8 ph[2], pl[2];
#pragma unroll
            for (int jt = 0; jt < 2; ++jt) {
                ph[jt] = *(const f16x8*)&PTH[SW(w*32 + jt*16 + c, kc*32 + quad*8)];
                pl[jt] = *(const f16x8*)&PTL[SW(w*32 + jt*16 + c, kc*32 + quad*8)];
            }
#pragma unroll
            for (int mtd = 0; mtd < 4; ++mtd) {
                f16x8 vh = *(const f16x8*)&VTH[SWV(mtd*16 + c, kc*32 + quad*8)];
                f16x8 vl = *(const f16x8*)&VTL[SWV(mtd*16 + c, kc*32 + quad*8)];
#pragma unroll
                for (int jt = 0; jt < 2; ++jt) {
                    f32x4 v = o[jt][mtd];
                    v = __builtin_amdgcn_mfma_f32_16x16x32_f16(vh, pl[jt], v, 0, 0, 0);
                    v = __builtin_amdgcn_mfma_f32_16x16x32_f16(vl, ph[jt], v, 0, 0, 0);
                    v = __builtin_amdgcn_mfma_f32_16x16x32_f16(vh, ph[jt], v, 0, 0, 0);
                    o[jt][mtd] = v;
                }
            }
        }

        // ---- stage prefetched tile ----
        if (kt < 31) {
            __syncthreads();   // all waves done reading KH/KL/VTH/VTL
#pragma unroll
            for (int i = 0; i < 4; ++i) {
                *(f16x4*)&KH[SW(r0 + i, c0)] = nh[i];
                *(f16x4*)&KL[SW(r0 + i, c0)] = nl[i];
            }
#pragma unroll
            for (int j = 0; j < 4; ++j) {
                *(f16x4*)&VTH[SWV(c0 + j, r0)] = (f16x4){nh[0][j], nh[1][j], nh[2][j], nh[3][j]};
                *(f16x4*)&VTL[SWV(c0 + j, r0)] = (f16x4){nl[0][j], nl[1][j], nl[2][j], nl[3][j]};
            }
            __syncthreads();
        }
    }

    // ---- epilogue: O^T C-layout -> AC rows + fused position sums ----
    const size_t gbase = ac_base(grp);
    const float inv[2] = {1.0f / l_st[0], 1.0f / l_st[1]};
    float part[4][4];
#pragma unroll
    for (int mtd = 0; mtd < 4; ++mtd)
#pragma unroll
        for (int i = 0; i < 4; ++i) part[mtd][i] = 0.f;
#pragma unroll
    for (int jt = 0; jt < 2; ++jt) {
        const int qrow = qt*128 + w*32 + jt*16 + c;
        float* dst = AC + gbase + ((size_t)((b*nseg + seg)*2048 + qrow)) * 256 + hg*64;
#pragma unroll
        for (int mtd = 0; mtd < 4; ++mtd) {
            float4 v = make_float4(o[jt][mtd][0]*inv[jt], o[jt][mtd][1]*inv[jt],
                                   o[jt][mtd][2]*inv[jt], o[jt][mtd][3]*inv[jt]);
            *(float4*)(dst + mtd*16 + quad*4) = v;
            part[mtd][0] += v.x; part[mtd][1] += v.y;
            part[mtd][2] += v.z; part[mtd][3] += v.w;
        }
    }
    // butterfly-reduce over the 16 c-lanes (quad bits 4,5 untouched)
#pragma unroll
    for (int mtd = 0; mtd < 4; ++mtd)
#pragma unroll
        for (int i = 0; i < 4; ++i) {
            float v = part[mtd][i];
            v += __shfl_xor(v, 1);
            v += __shfl_xor(v, 2);
            v += __shfl_xor(v, 4);
            v += __shfl_xor(v, 8);
            part[mtd][i] = v;
        }
    if (c == 0) {
        float* sbase = SUMS + ((grp << 1) + b) * 256 + hg*64 + quad*4;
#pragma unroll
        for (int mtd = 0; mtd < 4; ++mtd)
#pragma unroll
            for (int i = 0; i < 4; ++i)
                atomicAdd(&sbase[mtd*16 + i], part[mtd][i]);
    }
}

// ---------------------------------------------------------------------------
// Renormalize + scatter + /3 + LayerNorm, writing OLN as bf16 hi/lo split
// (fuses GEMM5's A-side conversion; values bit-identical to the fp32 path).
// ---------------------------------------------------------------------------
__device__ __forceinline__ float block_reduce_sum(float val, float* sdata) {
    __syncthreads();
#pragma unroll
    for (int o = 32; o > 0; o >>= 1) val += __shfl_down(val, o);
    const int lane = threadIdx.x & 63, wid = threadIdx.x >> 6;
    if (lane == 0) sdata[wid] = val;
    __syncthreads();
    return sdata[0] + sdata[1] + sdata[2] + sdata[3];
}

__global__ __launch_bounds__(256) void renorm_ln_kernel(
    const float* __restrict__ AC, const float* __restrict__ SUMS,
    const float* __restrict__ gamma, const float* __restrict__ beta,
    unsigned short* __restrict__ OLNH, unsigned short* __restrict__ OLNL) {
    __shared__ float sdata[4];
    const int pos = blockIdx.x;
    const int b = pos >> 13;
    const int n = pos & 8191;

    float v[3];
    int dms[3];
#pragma unroll
    for (int jj = 0; jj < 3; ++jj) {
        const int dm = threadIdx.x + (jj << 8);
        dms[jj] = dm;
        const int h = dm >> 6, d = dm & 63;
        const int grp = h >> 2, hg = h & 3;
        const int r = 1 << grp;
        const int p = n & ((2048 << grp) - 1);
        float val = 0.f;
        if ((p & (r - 1)) == grp) {
            const int nseg = 4 >> grp;
            const int seg  = n >> (11 + grp);
            const int j    = (p - grp) >> grp;
            const float s  = SUMS[((grp << 1) + b) * 256 + (hg << 6) + d];
            val = AC[ac_base(grp) + ((size_t)((b*nseg + seg)*2048 + j)) * 256 + (hg << 6) + d]
                  / (3.0f * s);
        }
        v[jj] = val;
    }

    const float tot = block_reduce_sum(v[0] + v[1] + v[2], sdata);
    const float mu  = tot * (1.0f / 768.0f);
    float sq = 0.f;
#pragma unroll
    for (int jj = 0; jj < 3; ++jj) {
        const float d0 = v[jj] - mu;
        sq += d0 * d0;
    }
    const float var  = block_reduce_sum(sq, sdata) * (1.0f / 768.0f);
    const float rstd = rsqrtf(var + 1e-5f);

    unsigned short* dh = OLNH + (size_t)pos * 768;
    unsigned short* dl = OLNL + (size_t)pos * 768;
#pragma unroll
    for (int jj = 0; jj < 3; ++jj) {
        const float val = (v[jj] - mu) * rstd * gamma[dms[jj]] + beta[dms[jj]];
        const unsigned short h = f2bf(val);
        dh[dms[jj]] = h;
        dl[dms[jj]] = f2bf(val - bf2f(h));
    }
}

// ---------------------------------------------------------------------------
extern "C" void kernel_launch(void* const* d_in, const int* in_sizes, int n_in,
                              void* d_out, int out_size, void* d_ws, size_t ws_size,
                              hipStream_t stream) {
    const float* x     = (const float*)d_in[0];
    const float* w_in  = (const float*)d_in[1];
    const float* b_in  = (const float*)d_in[2];
    const float* w_out = (const float*)d_in[3];
    const float* b_out = (const float*)d_in[4];
    const float* gamma = (const float*)d_in[5];
    const float* beta  = (const float*)d_in[6];
    float* out = (float*)d_out;

    float* ws   = (float*)d_ws;
    _Float16* Qh = (_Float16*)ws;                 // fp16 hi, 12.58M elems
    _Float16* Ql = (_Float16*)ws + QL_ELEM_OFF;   // fp16 lo
    float* AC   = ws + AC_OFF;
    float* SUMS = ws + SUMS_OFF;
    // W splits borrow the (currently dead) AC region
    unsigned short* WsplitH = (unsigned short*)(ws + AC_OFF);
    unsigned short* WsplitL = WsplitH + W_ELEMS;
    // OLN bf16 split reuses the Qh/Ql region (dead after attention)
    unsigned short* OLNH = (unsigned short*)ws;
    unsigned short* OLNL = OLNH + QL_ELEM_OFF;

    // 0) pre-split w_in (AC region is dead until attention)
    split_w_kernel<<<576, 256, 0, stream>>>(w_in, WsplitH, WsplitL);
    // 1) Q = x @ w_in.T + b_in, written as fp16 hi/lo split
    gemm_mfma_pre<<<dim3(128, 6), 256, 0, stream>>>(x, nullptr, nullptr,
                                                    WsplitH, WsplitL, b_in,
                                                    nullptr, Qh, Ql);
    // 2) dilated flash attention + fused position sums (SUMS zeroed first)
    (void)hipMemsetAsync(SUMS, 0, 1536 * sizeof(float), stream);
    attn_mfma_kernel<<<896, 256, 0, stream>>>(Qh, Ql, AC, SUMS);
    // 3) renorm + scatter + /3 + LayerNorm -> OLN bf16 hi/lo split
    renorm_ln_kernel<<<B_ * N_, 256, 0, stream>>>(AC, SUMS, gamma, beta,
                                                  OLNH, OLNL);
    // 4) pre-split w_out (AC is dead after renorm), then
    //    out = OLN @ w_out.T + b_out (fp32 epilogue)
    split_w_kernel<<<576, 256, 0, stream>>>(w_out, WsplitH, WsplitL);
    gemm_mfma_pre<<<dim3(128, 6), 256, 0, stream>>>(nullptr, OLNH, OLNL,
                                                    WsplitH, WsplitL, b_out,
                                                    out, nullptr, nullptr);
}

// Round 13
// 528.150 us; speedup vs baseline: 1.0153x; 1.0153x over previous
//
#include <hip/hip_runtime.h>
#include <hip/hip_bf16.h>
#include <math.h>

// Problem constants
#define B_   2
#define N_   8192
#define DM   768
#define NH   12
#define HD   64

// Workspace layout:
//   Qh (f16) at byte 0           : 12,582,912 f16  (= floats [0, 6291456))
//   Ql (f16) after it            : 12,582,912 f16
//   (OLNh/OLNl bf16 reuse Qh/Ql region after attention)
//   AC  at float 12,582,912, SUMS at float 19,922,944
//   W splits (589824 u16 x2) live in the AC region while it is dead.
#define QL_ELEM_OFF 12582912ull
#define AC_OFF      12582912ull
#define SUMS_OFF    19922944ull
#define W_ELEMS     589824

typedef short bf16x8 __attribute__((ext_vector_type(8)));
typedef _Float16 f16x8 __attribute__((ext_vector_type(8)));
typedef _Float16 f16x4 __attribute__((ext_vector_type(4)));
typedef float f32x4  __attribute__((ext_vector_type(4)));
typedef unsigned short u16x8 __attribute__((ext_vector_type(8)));
typedef unsigned short u16x4 __attribute__((ext_vector_type(4)));

__device__ __forceinline__ size_t ac_base(int grp) {
    return 8388608ull - (8388608ull >> grp);
}

__device__ __forceinline__ unsigned short f2bf(float f) {
    __hip_bfloat16 h = __float2bfloat16(f);
    return __builtin_bit_cast(unsigned short, h);
}
__device__ __forceinline__ float bf2f(unsigned short u) {
    __hip_bfloat16 h = __builtin_bit_cast(__hip_bfloat16, u);
    return __bfloat162float(h);
}
// fp16 RNE split: f ~= hi + lo with |f - hi - lo| <= 2^-22 |f|.
// NOTE (R6 lesson): the hi/lo split is REQUIRED on Q/K, P, and V -- the
// downstream renorm (x / x.sum over ~8192 positions) has cancellation in the
// denominator and amplifies per-element errors by up to ~3e4; dropping any
// lo term (fp16-only, 2^-11) blew absmax to 6.5 vs the 0.1 threshold.
__device__ __forceinline__ void split2h(float f, _Float16& h, _Float16& l) {
    h = (_Float16)f;
    l = (_Float16)(f - (float)h);
}

// XOR-chunk swizzle for 2-byte arrays, pitch 64 elements (128 B row).
// 16B chunks XORed by (row&7): b128 frag reads conflict-free.
#define SW(row, col) ((((row) << 6)) + ((((col) >> 3) ^ ((row) & 7)) << 3) + ((col) & 7))
// V^T variant: also XOR (row>>3). Validated R4/R7: conflict floor 3.67e6
// with this staging (vs 3.3e7 without).
#define SWV(row, col) ((((row) << 6)) + ((((col) >> 3) ^ ((row) & 7) ^ (((row) >> 3) & 7)) << 3) + ((col) & 7))

// ---------------------------------------------------------------------------
// One-shot fp32 -> bf16 hi/lo split for a 768x768 weight matrix.
// ---------------------------------------------------------------------------
__global__ __launch_bounds__(256) void split_w_kernel(
    const float* __restrict__ src, unsigned short* __restrict__ dh,
    unsigned short* __restrict__ dl) {
    const int i = (blockIdx.x * 256 + threadIdx.x) * 4;
    const float4 v = *(const float4*)(src + i);
    const float vv[4] = {v.x, v.y, v.z, v.w};
    u16x4 h, l;
#pragma unroll
    for (int j = 0; j < 4; ++j) {
        h[j] = f2bf(vv[j]);
        l[j] = f2bf(vv[j] - bf2f(h[j]));
    }
    *(u16x4*)(dh + i) = h;
    *(u16x4*)(dl + i) = l;
}

// ---------------------------------------------------------------------------
// Split-bf16 MFMA GEMM (NT). W is ALWAYS pre-split bf16 (WH/WL). A is fp32
// (Af != nullptr -- GEMM1) or pre-split bf16 (Ah/Al -- GEMM5).
// R13: XCD/A-reuse block remap. HW-linear id is x-major, so the 6 blocks
// sharing one 0.39 MB A-panel were 128 apart -> different XCDs -> A fetched
// ~6x from HBM (~300 MB/GEMM). vb=(bid&7)*96+(bid>>3) (bijective, 768=8*96)
// gives each XCD 16 consecutive row-panels x all 6 col-blocks: A-panel
// sharers co-resident on one XCD -> L2 hits. W (2.4 MB) is L2-resident
// under any ordering.
// ---------------------------------------------------------------------------
__global__ __launch_bounds__(256) void gemm_mfma_pre(
    const float* __restrict__ Af,
    const unsigned short* __restrict__ Ah, const unsigned short* __restrict__ Al,
    const unsigned short* __restrict__ WH, const unsigned short* __restrict__ WL,
    const float* __restrict__ bias, float* __restrict__ C,
    _Float16* __restrict__ Ch, _Float16* __restrict__ Cl) {
    __shared__ unsigned short AsH[128][40];
    __shared__ unsigned short AsL[128][40];
    __shared__ unsigned short WsH[128][40];
    __shared__ unsigned short WsL[128][40];

    const int t    = threadIdx.x;
    const int lane = t & 63;
    const int wv   = t >> 6;
    const int c    = lane & 15, q = lane >> 4;
    const int mw   = (wv & 1) * 64, nw = (wv >> 1) * 64;

    // XCD/A-reuse remap (see header comment)
    const int bid = blockIdx.x + gridDim.x * blockIdx.y;   // 0..767, x-major
    const int vb  = (bid & 7) * 96 + (bid >> 3);
    const int xb  = vb / 6;
    const int yb  = vb - xb * 6;
    const int m0  = xb * 128, n0 = yb * 128;

    const int srow = t >> 1;
    const int scol = (t & 1) * 16;
    const float* ap = Af ? Af + (size_t)(m0 + srow) * DM + scol : nullptr;
    const unsigned short* ahp = Ah ? Ah + (size_t)(m0 + srow) * DM + scol : nullptr;
    const unsigned short* alp = Al ? Al + (size_t)(m0 + srow) * DM + scol : nullptr;
    const unsigned short* whp = WH + (size_t)(n0 + srow) * DM + scol;
    const unsigned short* wlp = WL + (size_t)(n0 + srow) * DM + scol;

    f32x4 acc[4][4];
#pragma unroll
    for (int mi = 0; mi < 4; ++mi)
#pragma unroll
        for (int ni = 0; ni < 4; ++ni) {
            acc[mi][ni][0] = 0.f; acc[mi][ni][1] = 0.f;
            acc[mi][ni][2] = 0.f; acc[mi][ni][3] = 0.f;
        }

    for (int k0 = 0; k0 < DM; k0 += 32) {
        u16x8 wh0 = *(const u16x8*)(whp + k0);
        u16x8 wh1 = *(const u16x8*)(whp + k0 + 8);
        u16x8 wl0 = *(const u16x8*)(wlp + k0);
        u16x8 wl1 = *(const u16x8*)(wlp + k0 + 8);
        float av[16];
        u16x8 ah0, ah1, al0, al1;
        if (Af) {
            *(float4*)&av[0]  = *(const float4*)(ap + k0);
            *(float4*)&av[4]  = *(const float4*)(ap + k0 + 4);
            *(float4*)&av[8]  = *(const float4*)(ap + k0 + 8);
            *(float4*)&av[12] = *(const float4*)(ap + k0 + 12);
        } else {
            ah0 = *(const u16x8*)(ahp + k0);
            ah1 = *(const u16x8*)(ahp + k0 + 8);
            al0 = *(const u16x8*)(alp + k0);
            al1 = *(const u16x8*)(alp + k0 + 8);
        }
        __syncthreads();
        if (Af) {
#pragma unroll
            for (int i = 0; i < 16; ++i) {
                const float x = av[i];
                const unsigned short xh = f2bf(x);
                AsH[srow][scol + i] = xh;
                AsL[srow][scol + i] = f2bf(x - bf2f(xh));
            }
        } else {
            *(u16x8*)&AsH[srow][scol]     = ah0;
            *(u16x8*)&AsH[srow][scol + 8] = ah1;
            *(u16x8*)&AsL[srow][scol]     = al0;
            *(u16x8*)&AsL[srow][scol + 8] = al1;
        }
        *(u16x8*)&WsH[srow][scol]     = wh0;
        *(u16x8*)&WsH[srow][scol + 8] = wh1;
        *(u16x8*)&WsL[srow][scol]     = wl0;
        *(u16x8*)&WsL[srow][scol + 8] = wl1;
        __syncthreads();

        bf16x8 ah[4], al[4], bh[4], bl[4];
#pragma unroll
        for (int i = 0; i < 4; ++i) {
            ah[i] = *(const bf16x8*)&AsH[mw + i*16 + c][q*8];
            al[i] = *(const bf16x8*)&AsL[mw + i*16 + c][q*8];
            bh[i] = *(const bf16x8*)&WsH[nw + i*16 + c][q*8];
            bl[i] = *(const bf16x8*)&WsL[nw + i*16 + c][q*8];
        }
#pragma unroll
        for (int mi = 0; mi < 4; ++mi)
#pragma unroll
            for (int ni = 0; ni < 4; ++ni) {
                f32x4 v = acc[mi][ni];
                v = __builtin_amdgcn_mfma_f32_16x16x32_bf16(ah[mi], bl[ni], v, 0, 0, 0);
                v = __builtin_amdgcn_mfma_f32_16x16x32_bf16(al[mi], bh[ni], v, 0, 0, 0);
                v = __builtin_amdgcn_mfma_f32_16x16x32_bf16(ah[mi], bh[ni], v, 0, 0, 0);
                acc[mi][ni] = v;
            }
    }

#pragma unroll
    for (int ni = 0; ni < 4; ++ni) {
        const int col = n0 + nw + ni*16 + c;
        const float bv = bias[col];
#pragma unroll
        for (int mi = 0; mi < 4; ++mi)
#pragma unroll
            for (int r = 0; r < 4; ++r) {
                const int row = m0 + mw + mi*16 + q*4 + r;
                const float val = acc[mi][ni][r] + bv;
                if (Ch) {
                    _Float16 hh, ll;
                    split2h(val, hh, ll);
                    Ch[(size_t)row * DM + col] = hh;
                    Cl[(size_t)row * DM + col] = ll;
                } else {
                    C[(size_t)row * DM + col] = val;
                }
            }
    }
}

// ---------------------------------------------------------------------------
// Split-FP16 MFMA flash attention, S^T orientation, 128-query blocks.
// EXACT R7/R11 structure (best proven: 242.9 us). FROZEN: R10 proved not
// HBM-bound; R8/R9 proved 3 blocks/CU spills; R12 proved fused-sum atomics
// cost more than the sum_kernel they replace.
// ---------------------------------------------------------------------------
__global__ __launch_bounds__(256, 2) void attn_mfma_kernel(
    const _Float16* __restrict__ Qh, const _Float16* __restrict__ Ql,
    float* __restrict__ AC) {
    __shared__ __align__(16) _Float16 KH[4096],  KL[4096];   // K row-major [key][d]
    __shared__ __align__(16) _Float16 VTH[4096], VTL[4096];  // K transposed [d][key]
    __shared__ __align__(16) _Float16 PTH[8192], PTL[8192];  // P^T as [q(128)][k(64)]

    const int t    = threadIdx.x;
    const int lane = t & 63;
    const int w    = t >> 6;
    const int c    = lane & 15, quad = lane >> 4;

    // block -> (grp, b, seg, head, q-tile)
    const int bi  = blockIdx.x;
    const int qt  = bi & 15;           // 16 tiles of 128 queries per 2048
    const int bsh = bi >> 4;
    int grp, local;
    if (bsh < 32)      { grp = 0; local = bsh; }
    else if (bsh < 48) { grp = 1; local = bsh - 32; }
    else               { grp = 2; local = bsh - 48; }
    const int nseg = 4 >> grp;
    const int sseg = 2048 << grp;
    const int r    = 1 << grp;
    const int b    = local / (nseg * 4);
    const int rem  = local - b * nseg * 4;
    const int seg  = rem >> 2;
    const int hg   = rem & 3;
    const int head = grp * 4 + hg;

    const size_t row0 = (size_t)(b * N_ + seg * sseg + grp);
    const int hoff = head * HD;

    const int r0 = (t >> 4) * 4;   // staging rows (keys) 0..60
    const int c0 = (t & 15) * 4;   // staging cols (d)    0..60

    // ---- Q B-frags (loop-invariant): queries qt*128 + w*32 + jt*16 + c ----
    f16x8 qfh[2][2], qfl[2][2];   // [jt][kc]
#pragma unroll
    for (int jt = 0; jt < 2; ++jt) {
        const int qrow = qt*128 + w*32 + jt*16 + c;
        const size_t qoff = (row0 + (size_t)qrow * r) * DM + hoff;
#pragma unroll
        for (int kc = 0; kc < 2; ++kc) {
            f16x8 h = *(const f16x8*)(Qh + qoff + kc*32 + quad*8);
            f16x8 l = *(const f16x8*)(Ql + qoff + kc*32 + quad*8);
            qfh[jt][kc] = h * (_Float16)0.125f;   // fold 1/sqrt(64), exact pow2
            qfl[jt][kc] = l * (_Float16)0.125f;
        }
    }

    // ---- stage K-tile 0 ----
    {
        f16x4 hh[4], ll[4];
#pragma unroll
        for (int i = 0; i < 4; ++i) {
            const size_t off = (row0 + (size_t)(r0 + i) * r) * DM + hoff + c0;
            hh[i] = *(const f16x4*)(Qh + off);
            ll[i] = *(const f16x4*)(Ql + off);
        }
#pragma unroll
        for (int i = 0; i < 4; ++i) {
            *(f16x4*)&KH[SW(r0 + i, c0)] = hh[i];
            *(f16x4*)&KL[SW(r0 + i, c0)] = ll[i];
        }
#pragma unroll
        for (int j = 0; j < 4; ++j) {
            *(f16x4*)&VTH[SWV(c0 + j, r0)] = (f16x4){hh[0][j], hh[1][j], hh[2][j], hh[3][j]};
            *(f16x4*)&VTL[SWV(c0 + j, r0)] = (f16x4){ll[0][j], ll[1][j], ll[2][j], ll[3][j]};
        }
    }
    __syncthreads();

    float m_st[2] = {-1e30f, -1e30f};
    float l_st[2] = {0.f, 0.f};
    f32x4 o[2][4];
#pragma unroll
    for (int jt = 0; jt < 2; ++jt)
#pragma unroll
        for (int i = 0; i < 4; ++i) {
            o[jt][i][0] = 0.f; o[jt][i][1] = 0.f;
            o[jt][i][2] = 0.f; o[jt][i][3] = 0.f;
        }

    for (int kt = 0; kt < 32; ++kt) {
        // prefetch next K-tile into registers
        f16x4 nh[4], nl[4];
        if (kt < 31) {
#pragma unroll
            for (int i = 0; i < 4; ++i) {
                const size_t off = (row0 + (size_t)((kt+1)*64 + r0 + i) * r) * DM + hoff + c0;
                nh[i] = *(const f16x4*)(Qh + off);
                nl[i] = *(const f16x4*)(Ql + off);
            }
        }

        // ---- S^T[k][q]: A = K rows (shared across jt), B = Q^T ----
        f32x4 s[2][4];
#pragma unroll
        for (int jt = 0; jt < 2; ++jt)
#pragma unroll
            for (int mt = 0; mt < 4; ++mt) {
                s[jt][mt][0] = 0.f; s[jt][mt][1] = 0.f;
                s[jt][mt][2] = 0.f; s[jt][mt][3] = 0.f;
            }
#pragma unroll
        for (int kc = 0; kc < 2; ++kc)
#pragma unroll
            for (int mt = 0; mt < 4; ++mt) {
                f16x8 ah = *(const f16x8*)&KH[SW(mt*16 + c, kc*32 + quad*8)];
                f16x8 al = *(const f16x8*)&KL[SW(mt*16 + c, kc*32 + quad*8)];
#pragma unroll
                for (int jt = 0; jt < 2; ++jt) {
                    f32x4 v = s[jt][mt];
                    v = __builtin_amdgcn_mfma_f32_16x16x32_f16(ah, qfl[jt][kc], v, 0, 0, 0);
                    v = __builtin_amdgcn_mfma_f32_16x16x32_f16(al, qfh[jt][kc], v, 0, 0, 0);
                    v = __builtin_amdgcn_mfma_f32_16x16x32_f16(ah, qfh[jt][kc], v, 0, 0, 0);
                    s[jt][mt] = v;
                }
            }

        // ---- per-lane online softmax (independent per jt) + P^T write ----
#pragma unroll
        for (int jt = 0; jt < 2; ++jt) {
            float mloc = s[jt][0][0];
#pragma unroll
            for (int mt = 0; mt < 4; ++mt)
#pragma unroll
                for (int rg = 0; rg < 4; ++rg) mloc = fmaxf(mloc, s[jt][mt][rg]);
            mloc = fmaxf(mloc, __shfl_xor(mloc, 16));
            mloc = fmaxf(mloc, __shfl_xor(mloc, 32));
            // wave-uniform skip: when no query's max moved, alpha == 1 exactly
            if (!__all(mloc <= m_st[jt])) {
                const float mnew  = fmaxf(m_st[jt], mloc);
                const float alpha = __expf(m_st[jt] - mnew);
                m_st[jt] = mnew;
                l_st[jt] *= alpha;
#pragma unroll
                for (int mtd = 0; mtd < 4; ++mtd) {
                    o[jt][mtd][0] *= alpha; o[jt][mtd][1] *= alpha;
                    o[jt][mtd][2] *= alpha; o[jt][mtd][3] *= alpha;
                }
            }
            const float mcur = m_st[jt];
            float psum = 0.f;
            const int prow = w*32 + jt*16 + c;
#pragma unroll
            for (int mt = 0; mt < 4; ++mt) {
                f16x4 hh, ll;
#pragma unroll
                for (int rg = 0; rg < 4; ++rg) {
                    const float pv = __expf(s[jt][mt][rg] - mcur);
                    psum += pv;
                    _Float16 th, tl;
                    split2h(pv, th, tl);
                    hh[rg] = th;
                    ll[rg] = tl;
                }
                *(f16x4*)&PTH[SW(prow, mt*16 + quad*4)] = hh;
                *(f16x4*)&PTL[SW(prow, mt*16 + quad*4)] = ll;
            }
            psum += __shfl_xor(psum, 16);
            psum += __shfl_xor(psum, 32);
            l_st[jt] += psum;
        }
        // wave-private P^T rows: same-wave write->read, no barrier needed

        // ---- PV: O^T[d][q] += V^T P^T (V^T frags shared across jt) ----
#pragma unroll
        for (int kc = 0; kc < 2; ++kc) {
            f16x8 ph[2], pl[2];
#pragma unroll
            for (int jt = 0; jt < 2; ++jt) {
                ph[jt] = *(const f16x8*)&PTH[SW(w*32 + jt*16 + c, kc*32 + quad*8)];
                pl[jt] = *(const f16x8*)&PTL[SW(w*32 + jt*16 + c, kc*32 + quad*8)];
            }
#pragma unroll
            for (int mtd = 0; mtd < 4; ++mtd) {
                f16x8 vh = *(const f16x8*)&VTH[SWV(mtd*16 + c, kc*32 + quad*8)];
                f16x8 vl = *(const f16x8*)&VTL[SWV(mtd*16 + c, kc*32 + quad*8)];
#pragma unroll
                for (int jt = 0; jt < 2; ++jt) {
                    f32x4 v = o[jt][mtd];
                    v = __builtin_amdgcn_mfma_f32_16x16x32_f16(vh, pl[jt], v, 0, 0, 0);
                    v = __builtin_amdgcn_mfma_f32_16x16x32_f16(vl, ph[jt], v, 0, 0, 0);
                    v = __builtin_amdgcn_mfma_f32_16x16x32_f16(vh, ph[jt], v, 0, 0, 0);
                    o[jt][mtd] = v;
                }
            }
        }

        // ---- stage prefetched tile ----
        if (kt < 31) {
            __syncthreads();   // all waves done reading KH/KL/VTH/VTL
#pragma unroll
            for (int i = 0; i < 4; ++i) {
                *(f16x4*)&KH[SW(r0 + i, c0)] = nh[i];
                *(f16x4*)&KL[SW(r0 + i, c0)] = nl[i];
            }
#pragma unroll
            for (int j = 0; j < 4; ++j) {
                *(f16x4*)&VTH[SWV(c0 + j, r0)] = (f16x4){nh[0][j], nh[1][j], nh[2][j], nh[3][j]};
                *(f16x4*)&VTL[SWV(c0 + j, r0)] = (f16x4){nl[0][j], nl[1][j], nl[2][j], nl[3][j]};
            }
            __syncthreads();
        }
    }

    // ---- epilogue: O^T C-layout -> AC rows ----
    const size_t gbase = ac_base(grp);
#pragma unroll
    for (int jt = 0; jt < 2; ++jt) {
        const float inv = 1.0f / l_st[jt];
        const int qrow = qt*128 + w*32 + jt*16 + c;
        float* dst = AC + gbase + ((size_t)((b*nseg + seg)*2048 + qrow)) * 256 + hg*64;
#pragma unroll
        for (int mtd = 0; mtd < 4; ++mtd) {
            float4 v = make_float4(o[jt][mtd][0]*inv, o[jt][mtd][1]*inv,
                                   o[jt][mtd][2]*inv, o[jt][mtd][3]*inv);
            *(float4*)(dst + mtd*16 + quad*4) = v;
        }
    }
}

// ---------------------------------------------------------------------------
// Per-(group,b,head-in-group,d) sums over all positions. (restored from R11;
// R12 proved in-epilogue atomic fusion is slower.)
// ---------------------------------------------------------------------------
__global__ __launch_bounds__(256) void sum_kernel(
    const float* __restrict__ AC, float* __restrict__ SUMS) {
    const int bi = blockIdx.x;
    int grp, local;
    if (bi < 64)      { grp = 0; local = bi; }
    else if (bi < 96) { grp = 1; local = bi - 64; }
    else              { grp = 2; local = bi - 96; }
    const int chunks = 32 >> grp;
    const int b  = local / chunks;
    const int ch = local - b * chunks;
    const int P  = 8192 >> grp;
    const size_t base = ac_base(grp) + ((size_t)b * P + ch * 256) * 256 + threadIdx.x;
    float acc = 0.f;
    for (int p = 0; p < 256; ++p) acc += AC[base + (size_t)p * 256];
    atomicAdd(&SUMS[((grp << 1) + b) * 256 + threadIdx.x], acc);
}

// ---------------------------------------------------------------------------
// Renormalize + scatter + /3 + LayerNorm, writing OLN as bf16 hi/lo split
// (fuses GEMM5's A-side conversion; values bit-identical to the fp32 path).
// ---------------------------------------------------------------------------
__device__ __forceinline__ float block_reduce_sum(float val, float* sdata) {
    __syncthreads();
#pragma unroll
    for (int o = 32; o > 0; o >>= 1) val += __shfl_down(val, o);
    const int lane = threadIdx.x & 63, wid = threadIdx.x >> 6;
    if (lane == 0) sdata[wid] = val;
    __syncthreads();
    return sdata[0] + sdata[1] + sdata[2] + sdata[3];
}

__global__ __launch_bounds__(256) void renorm_ln_kernel(
    const float* __restrict__ AC, const float* __restrict__ SUMS,
    const float* __restrict__ gamma, const float* __restrict__ beta,
    unsigned short* __restrict__ OLNH, unsigned short* __restrict__ OLNL) {
    __shared__ float sdata[4];
    const int pos = blockIdx.x;
    const int b = pos >> 13;
    const int n = pos & 8191;

    float v[3];
    int dms[3];
#pragma unroll
    for (int jj = 0; jj < 3; ++jj) {
        const int dm = threadIdx.x + (jj << 8);
        dms[jj] = dm;
        const int h = dm >> 6, d = dm & 63;
        const int grp = h >> 2, hg = h & 3;
        const int r = 1 << grp;
        const int p = n & ((2048 << grp) - 1);
        float val = 0.f;
        if ((p & (r - 1)) == grp) {
            const int nseg = 4 >> grp;
            const int seg  = n >> (11 + grp);
            const int j    = (p - grp) >> grp;
            const float s  = SUMS[((grp << 1) + b) * 256 + (hg << 6) + d];
            val = AC[ac_base(grp) + ((size_t)((b*nseg + seg)*2048 + j)) * 256 + (hg << 6) + d]
                  / (3.0f * s);
        }
        v[jj] = val;
    }

    const float tot = block_reduce_sum(v[0] + v[1] + v[2], sdata);
    const float mu  = tot * (1.0f / 768.0f);
    float sq = 0.f;
#pragma unroll
    for (int jj = 0; jj < 3; ++jj) {
        const float d0 = v[jj] - mu;
        sq += d0 * d0;
    }
    const float var  = block_reduce_sum(sq, sdata) * (1.0f / 768.0f);
    const float rstd = rsqrtf(var + 1e-5f);

    unsigned short* dh = OLNH + (size_t)pos * 768;
    unsigned short* dl = OLNL + (size_t)pos * 768;
#pragma unroll
    for (int jj = 0; jj < 3; ++jj) {
        const float val = (v[jj] - mu) * rstd * gamma[dms[jj]] + beta[dms[jj]];
        const unsigned short h = f2bf(val);
        dh[dms[jj]] = h;
        dl[dms[jj]] = f2bf(val - bf2f(h));
    }
}

// ---------------------------------------------------------------------------
extern "C" void kernel_launch(void* const* d_in, const int* in_sizes, int n_in,
                              void* d_out, int out_size, void* d_ws, size_t ws_size,
                              hipStream_t stream) {
    const float* x     = (const float*)d_in[0];
    const float* w_in  = (const float*)d_in[1];
    const float* b_in  = (const float*)d_in[2];
    const float* w_out = (const float*)d_in[3];
    const float* b_out = (const float*)d_in[4];
    const float* gamma = (const float*)d_in[5];
    const float* beta  = (const float*)d_in[6];
    float* out = (float*)d_out;

    float* ws   = (float*)d_ws;
    _Float16* Qh = (_Float16*)ws;                 // fp16 hi, 12.58M elems
    _Float16* Ql = (_Float16*)ws + QL_ELEM_OFF;   // fp16 lo
    float* AC   = ws + AC_OFF;
    float* SUMS = ws + SUMS_OFF;
    // W splits borrow the (currently dead) AC region
    unsigned short* WsplitH = (unsigned short*)(ws + AC_OFF);
    unsigned short* WsplitL = WsplitH + W_ELEMS;
    // OLN bf16 split reuses the Qh/Ql region (dead after attention)
    unsigned short* OLNH = (unsigned short*)ws;
    unsigned short* OLNL = OLNH + QL_ELEM_OFF;

    // 0) pre-split w_in (AC region is dead until attention)
    split_w_kernel<<<576, 256, 0, stream>>>(w_in, WsplitH, WsplitL);
    // 1) Q = x @ w_in.T + b_in, written as fp16 hi/lo split
    gemm_mfma_pre<<<dim3(128, 6), 256, 0, stream>>>(x, nullptr, nullptr,
                                                    WsplitH, WsplitL, b_in,
                                                    nullptr, Qh, Ql);
    // 2) dilated flash attention (exact R7/R11, frozen)
    attn_mfma_kernel<<<896, 256, 0, stream>>>(Qh, Ql, AC);
    // 3) per-(group,b,h,d) position sums
    (void)hipMemsetAsync(SUMS, 0, 1536 * sizeof(float), stream);
    sum_kernel<<<112, 256, 0, stream>>>(AC, SUMS);
    // 4) renorm + scatter + /3 + LayerNorm -> OLN bf16 hi/lo split
    renorm_ln_kernel<<<B_ * N_, 256, 0, stream>>>(AC, SUMS, gamma, beta,
                                                  OLNH, OLNL);
    // 5) pre-split w_out (AC is dead after renorm), then
    //    out = OLN @ w_out.T + b_out (fp32 epilogue)
    split_w_kernel<<<576, 256, 0, stream>>>(w_out, WsplitH, WsplitL);
    gemm_mfma_pre<<<dim3(128, 6), 256, 0, stream>>>(nullptr, OLNH, OLNL,
                                                    WsplitH, WsplitL, b_out,
                                                    out, nullptr, nullptr);
}

// Round 14
// 504.486 us; speedup vs baseline: 1.0629x; 1.0469x over previous
//
#include <hip/hip_runtime.h>
#include <hip/hip_bf16.h>
#include <math.h>

// Problem constants
#define B_   2
#define N_   8192
#define DM   768
#define NH   12
#define HD   64

// Workspace layout:
//   Qh (f16) at byte 0           : 12,582,912 f16  (= floats [0, 6291456))
//   Ql (f16) after it            : 12,582,912 f16
//   (OLNh/OLNl bf16 reuse Qh/Ql region after attention)
//   AC  at float 12,582,912, SUMS at float 19,922,944
//   W splits (589824 u16 x2) live in the AC region while it is dead.
#define QL_ELEM_OFF 12582912ull
#define AC_OFF      12582912ull
#define SUMS_OFF    19922944ull
#define W_ELEMS     589824

typedef short bf16x8 __attribute__((ext_vector_type(8)));
typedef _Float16 f16x8 __attribute__((ext_vector_type(8)));
typedef _Float16 f16x4 __attribute__((ext_vector_type(4)));
typedef float f32x4  __attribute__((ext_vector_type(4)));
typedef unsigned short u16x8 __attribute__((ext_vector_type(8)));
typedef unsigned short u16x4 __attribute__((ext_vector_type(4)));

__device__ __forceinline__ size_t ac_base(int grp) {
    return 8388608ull - (8388608ull >> grp);
}

__device__ __forceinline__ unsigned short f2bf(float f) {
    __hip_bfloat16 h = __float2bfloat16(f);
    return __builtin_bit_cast(unsigned short, h);
}
__device__ __forceinline__ float bf2f(unsigned short u) {
    __hip_bfloat16 h = __builtin_bit_cast(__hip_bfloat16, u);
    return __bfloat162float(h);
}
// fp16 RNE split: f ~= hi + lo with |f - hi - lo| <= 2^-22 |f|.
// NOTE (R6 lesson): the hi/lo split is REQUIRED on Q/K, P, and V -- the
// downstream renorm (x / x.sum over ~8192 positions) has cancellation in the
// denominator and amplifies per-element errors by up to ~3e4; dropping any
// lo term (fp16-only, 2^-11) blew absmax to 6.5 vs the 0.1 threshold.
__device__ __forceinline__ void split2h(float f, _Float16& h, _Float16& l) {
    h = (_Float16)f;
    l = (_Float16)(f - (float)h);
}

// XOR-chunk swizzle for 2-byte arrays, pitch 64 elements (128 B row).
// 16B chunks XORed by (row&7): b128 frag reads conflict-free.
#define SW(row, col) ((((row) << 6)) + ((((col) >> 3) ^ ((row) & 7)) << 3) + ((col) & 7))
// V^T variant: also XOR (row>>3). Validated R4/R7: conflict floor 3.67e6
// with this staging (vs 3.3e7 without).
#define SWV(row, col) ((((row) << 6)) + ((((col) >> 3) ^ ((row) & 7) ^ (((row) >> 3) & 7)) << 3) + ((col) & 7))

// ---------------------------------------------------------------------------
// One-shot fp32 -> bf16 hi/lo split for a 768x768 weight matrix.
// ---------------------------------------------------------------------------
__global__ __launch_bounds__(256) void split_w_kernel(
    const float* __restrict__ src, unsigned short* __restrict__ dh,
    unsigned short* __restrict__ dl) {
    const int i = (blockIdx.x * 256 + threadIdx.x) * 4;
    const float4 v = *(const float4*)(src + i);
    const float vv[4] = {v.x, v.y, v.z, v.w};
    u16x4 h, l;
#pragma unroll
    for (int j = 0; j < 4; ++j) {
        h[j] = f2bf(vv[j]);
        l[j] = f2bf(vv[j] - bf2f(h[j]));
    }
    *(u16x4*)(dh + i) = h;
    *(u16x4*)(dl + i) = l;
}

// ---------------------------------------------------------------------------
// Split-bf16 MFMA GEMM (NT). W is ALWAYS pre-split bf16 (WH/WL). A is fp32
// (Af != nullptr -- GEMM1) or pre-split bf16 (Ah/Al -- GEMM5).
// R14: REGISTER PREFETCH (attention's proven pattern). Previously K-step k's
// global loads issued after K-step k-1's MFMAs -> every step exposed full
// L2/HBM latency. Now: stage from regs -> barrier -> issue loads for k+32 ->
// MFMA (loads fly under MFMA). Same instructions/values, reordered issue.
// Block mapping reverted to direct (R13's A-panel remap regressed ~9 us).
// ---------------------------------------------------------------------------
__global__ __launch_bounds__(256) void gemm_mfma_pre(
    const float* __restrict__ Af,
    const unsigned short* __restrict__ Ah, const unsigned short* __restrict__ Al,
    const unsigned short* __restrict__ WH, const unsigned short* __restrict__ WL,
    const float* __restrict__ bias, float* __restrict__ C,
    _Float16* __restrict__ Ch, _Float16* __restrict__ Cl) {
    __shared__ unsigned short AsH[128][40];
    __shared__ unsigned short AsL[128][40];
    __shared__ unsigned short WsH[128][40];
    __shared__ unsigned short WsL[128][40];

    const int t    = threadIdx.x;
    const int lane = t & 63;
    const int wv   = t >> 6;
    const int c    = lane & 15, q = lane >> 4;
    const int mw   = (wv & 1) * 64, nw = (wv >> 1) * 64;
    const int m0   = blockIdx.x * 128, n0 = blockIdx.y * 128;

    const int srow = t >> 1;
    const int scol = (t & 1) * 16;
    const float* ap = Af ? Af + (size_t)(m0 + srow) * DM + scol : nullptr;
    const unsigned short* ahp = Ah ? Ah + (size_t)(m0 + srow) * DM + scol : nullptr;
    const unsigned short* alp = Al ? Al + (size_t)(m0 + srow) * DM + scol : nullptr;
    const unsigned short* whp = WH + (size_t)(n0 + srow) * DM + scol;
    const unsigned short* wlp = WL + (size_t)(n0 + srow) * DM + scol;

    f32x4 acc[4][4];
#pragma unroll
    for (int mi = 0; mi < 4; ++mi)
#pragma unroll
        for (int ni = 0; ni < 4; ++ni) {
            acc[mi][ni][0] = 0.f; acc[mi][ni][1] = 0.f;
            acc[mi][ni][2] = 0.f; acc[mi][ni][3] = 0.f;
        }

    // software-prefetch registers; load K-step 0
    u16x8 wh0, wh1, wl0, wl1;
    float av[16];
    u16x8 ah0, ah1, al0, al1;
    wh0 = *(const u16x8*)(whp);
    wh1 = *(const u16x8*)(whp + 8);
    wl0 = *(const u16x8*)(wlp);
    wl1 = *(const u16x8*)(wlp + 8);
    if (Af) {
        *(float4*)&av[0]  = *(const float4*)(ap);
        *(float4*)&av[4]  = *(const float4*)(ap + 4);
        *(float4*)&av[8]  = *(const float4*)(ap + 8);
        *(float4*)&av[12] = *(const float4*)(ap + 12);
    } else {
        ah0 = *(const u16x8*)(ahp);
        ah1 = *(const u16x8*)(ahp + 8);
        al0 = *(const u16x8*)(alp);
        al1 = *(const u16x8*)(alp + 8);
    }

    for (int k0 = 0; k0 < DM; k0 += 32) {
        __syncthreads();   // prior iteration's LDS reads complete
        if (Af) {
#pragma unroll
            for (int i = 0; i < 16; ++i) {
                const float x = av[i];
                const unsigned short xh = f2bf(x);
                AsH[srow][scol + i] = xh;
                AsL[srow][scol + i] = f2bf(x - bf2f(xh));
            }
        } else {
            *(u16x8*)&AsH[srow][scol]     = ah0;
            *(u16x8*)&AsH[srow][scol + 8] = ah1;
            *(u16x8*)&AsL[srow][scol]     = al0;
            *(u16x8*)&AsL[srow][scol + 8] = al1;
        }
        *(u16x8*)&WsH[srow][scol]     = wh0;
        *(u16x8*)&WsH[srow][scol + 8] = wh1;
        *(u16x8*)&WsL[srow][scol]     = wl0;
        *(u16x8*)&WsL[srow][scol + 8] = wl1;
        __syncthreads();

        // issue next K-step's loads BEFORE the MFMAs (latency hidden)
        const int kn = k0 + 32;
        if (kn < DM) {
            wh0 = *(const u16x8*)(whp + kn);
            wh1 = *(const u16x8*)(whp + kn + 8);
            wl0 = *(const u16x8*)(wlp + kn);
            wl1 = *(const u16x8*)(wlp + kn + 8);
            if (Af) {
                *(float4*)&av[0]  = *(const float4*)(ap + kn);
                *(float4*)&av[4]  = *(const float4*)(ap + kn + 4);
                *(float4*)&av[8]  = *(const float4*)(ap + kn + 8);
                *(float4*)&av[12] = *(const float4*)(ap + kn + 12);
            } else {
                ah0 = *(const u16x8*)(ahp + kn);
                ah1 = *(const u16x8*)(ahp + kn + 8);
                al0 = *(const u16x8*)(alp + kn);
                al1 = *(const u16x8*)(alp + kn + 8);
            }
        }

        bf16x8 ah[4], al[4], bh[4], bl[4];
#pragma unroll
        for (int i = 0; i < 4; ++i) {
            ah[i] = *(const bf16x8*)&AsH[mw + i*16 + c][q*8];
            al[i] = *(const bf16x8*)&AsL[mw + i*16 + c][q*8];
            bh[i] = *(const bf16x8*)&WsH[nw + i*16 + c][q*8];
            bl[i] = *(const bf16x8*)&WsL[nw + i*16 + c][q*8];
        }
#pragma unroll
        for (int mi = 0; mi < 4; ++mi)
#pragma unroll
            for (int ni = 0; ni < 4; ++ni) {
                f32x4 v = acc[mi][ni];
                v = __builtin_amdgcn_mfma_f32_16x16x32_bf16(ah[mi], bl[ni], v, 0, 0, 0);
                v = __builtin_amdgcn_mfma_f32_16x16x32_bf16(al[mi], bh[ni], v, 0, 0, 0);
                v = __builtin_amdgcn_mfma_f32_16x16x32_bf16(ah[mi], bh[ni], v, 0, 0, 0);
                acc[mi][ni] = v;
            }
    }

#pragma unroll
    for (int ni = 0; ni < 4; ++ni) {
        const int col = n0 + nw + ni*16 + c;
        const float bv = bias[col];
#pragma unroll
        for (int mi = 0; mi < 4; ++mi)
#pragma unroll
            for (int r = 0; r < 4; ++r) {
                const int row = m0 + mw + mi*16 + q*4 + r;
                const float val = acc[mi][ni][r] + bv;
                if (Ch) {
                    _Float16 hh, ll;
                    split2h(val, hh, ll);
                    Ch[(size_t)row * DM + col] = hh;
                    Cl[(size_t)row * DM + col] = ll;
                } else {
                    C[(size_t)row * DM + col] = val;
                }
            }
    }
}

// ---------------------------------------------------------------------------
// Split-FP16 MFMA flash attention, S^T orientation, 128-query blocks.
// EXACT R7/R11 structure (best proven: 242.9 us). FROZEN: R10 proved not
// HBM-bound; R8/R9 proved 3 blocks/CU spills; R12 proved fused-sum atomics
// cost more than the sum_kernel they replace.
// ---------------------------------------------------------------------------
__global__ __launch_bounds__(256, 2) void attn_mfma_kernel(
    const _Float16* __restrict__ Qh, const _Float16* __restrict__ Ql,
    float* __restrict__ AC) {
    __shared__ __align__(16) _Float16 KH[4096],  KL[4096];   // K row-major [key][d]
    __shared__ __align__(16) _Float16 VTH[4096], VTL[4096];  // K transposed [d][key]
    __shared__ __align__(16) _Float16 PTH[8192], PTL[8192];  // P^T as [q(128)][k(64)]

    const int t    = threadIdx.x;
    const int lane = t & 63;
    const int w    = t >> 6;
    const int c    = lane & 15, quad = lane >> 4;

    // block -> (grp, b, seg, head, q-tile)
    const int bi  = blockIdx.x;
    const int qt  = bi & 15;           // 16 tiles of 128 queries per 2048
    const int bsh = bi >> 4;
    int grp, local;
    if (bsh < 32)      { grp = 0; local = bsh; }
    else if (bsh < 48) { grp = 1; local = bsh - 32; }
    else               { grp = 2; local = bsh - 48; }
    const int nseg = 4 >> grp;
    const int sseg = 2048 << grp;
    const int r    = 1 << grp;
    const int b    = local / (nseg * 4);
    const int rem  = local - b * nseg * 4;
    const int seg  = rem >> 2;
    const int hg   = rem & 3;
    const int head = grp * 4 + hg;

    const size_t row0 = (size_t)(b * N_ + seg * sseg + grp);
    const int hoff = head * HD;

    const int r0 = (t >> 4) * 4;   // staging rows (keys) 0..60
    const int c0 = (t & 15) * 4;   // staging cols (d)    0..60

    // ---- Q B-frags (loop-invariant): queries qt*128 + w*32 + jt*16 + c ----
    f16x8 qfh[2][2], qfl[2][2];   // [jt][kc]
#pragma unroll
    for (int jt = 0; jt < 2; ++jt) {
        const int qrow = qt*128 + w*32 + jt*16 + c;
        const size_t qoff = (row0 + (size_t)qrow * r) * DM + hoff;
#pragma unroll
        for (int kc = 0; kc < 2; ++kc) {
            f16x8 h = *(const f16x8*)(Qh + qoff + kc*32 + quad*8);
            f16x8 l = *(const f16x8*)(Ql + qoff + kc*32 + quad*8);
            qfh[jt][kc] = h * (_Float16)0.125f;   // fold 1/sqrt(64), exact pow2
            qfl[jt][kc] = l * (_Float16)0.125f;
        }
    }

    // ---- stage K-tile 0 ----
    {
        f16x4 hh[4], ll[4];
#pragma unroll
        for (int i = 0; i < 4; ++i) {
            const size_t off = (row0 + (size_t)(r0 + i) * r) * DM + hoff + c0;
            hh[i] = *(const f16x4*)(Qh + off);
            ll[i] = *(const f16x4*)(Ql + off);
        }
#pragma unroll
        for (int i = 0; i < 4; ++i) {
            *(f16x4*)&KH[SW(r0 + i, c0)] = hh[i];
            *(f16x4*)&KL[SW(r0 + i, c0)] = ll[i];
        }
#pragma unroll
        for (int j = 0; j < 4; ++j) {
            *(f16x4*)&VTH[SWV(c0 + j, r0)] = (f16x4){hh[0][j], hh[1][j], hh[2][j], hh[3][j]};
            *(f16x4*)&VTL[SWV(c0 + j, r0)] = (f16x4){ll[0][j], ll[1][j], ll[2][j], ll[3][j]};
        }
    }
    __syncthreads();

    float m_st[2] = {-1e30f, -1e30f};
    float l_st[2] = {0.f, 0.f};
    f32x4 o[2][4];
#pragma unroll
    for (int jt = 0; jt < 2; ++jt)
#pragma unroll
        for (int i = 0; i < 4; ++i) {
            o[jt][i][0] = 0.f; o[jt][i][1] = 0.f;
            o[jt][i][2] = 0.f; o[jt][i][3] = 0.f;
        }

    for (int kt = 0; kt < 32; ++kt) {
        // prefetch next K-tile into registers
        f16x4 nh[4], nl[4];
        if (kt < 31) {
#pragma unroll
            for (int i = 0; i < 4; ++i) {
                const size_t off = (row0 + (size_t)((kt+1)*64 + r0 + i) * r) * DM + hoff + c0;
                nh[i] = *(const f16x4*)(Qh + off);
                nl[i] = *(const f16x4*)(Ql + off);
            }
        }

        // ---- S^T[k][q]: A = K rows (shared across jt), B = Q^T ----
        f32x4 s[2][4];
#pragma unroll
        for (int jt = 0; jt < 2; ++jt)
#pragma unroll
            for (int mt = 0; mt < 4; ++mt) {
                s[jt][mt][0] = 0.f; s[jt][mt][1] = 0.f;
                s[jt][mt][2] = 0.f; s[jt][mt][3] = 0.f;
            }
#pragma unroll
        for (int kc = 0; kc < 2; ++kc)
#pragma unroll
            for (int mt = 0; mt < 4; ++mt) {
                f16x8 ah = *(const f16x8*)&KH[SW(mt*16 + c, kc*32 + quad*8)];
                f16x8 al = *(const f16x8*)&KL[SW(mt*16 + c, kc*32 + quad*8)];
#pragma unroll
                for (int jt = 0; jt < 2; ++jt) {
                    f32x4 v = s[jt][mt];
                    v = __builtin_amdgcn_mfma_f32_16x16x32_f16(ah, qfl[jt][kc], v, 0, 0, 0);
                    v = __builtin_amdgcn_mfma_f32_16x16x32_f16(al, qfh[jt][kc], v, 0, 0, 0);
                    v = __builtin_amdgcn_mfma_f32_16x16x32_f16(ah, qfh[jt][kc], v, 0, 0, 0);
                    s[jt][mt] = v;
                }
            }

        // ---- per-lane online softmax (independent per jt) + P^T write ----
#pragma unroll
        for (int jt = 0; jt < 2; ++jt) {
            float mloc = s[jt][0][0];
#pragma unroll
            for (int mt = 0; mt < 4; ++mt)
#pragma unroll
                for (int rg = 0; rg < 4; ++rg) mloc = fmaxf(mloc, s[jt][mt][rg]);
            mloc = fmaxf(mloc, __shfl_xor(mloc, 16));
            mloc = fmaxf(mloc, __shfl_xor(mloc, 32));
            // wave-uniform skip: when no query's max moved, alpha == 1 exactly
            if (!__all(mloc <= m_st[jt])) {
                const float mnew  = fmaxf(m_st[jt], mloc);
                const float alpha = __expf(m_st[jt] - mnew);
                m_st[jt] = mnew;
                l_st[jt] *= alpha;
#pragma unroll
                for (int mtd = 0; mtd < 4; ++mtd) {
                    o[jt][mtd][0] *= alpha; o[jt][mtd][1] *= alpha;
                    o[jt][mtd][2] *= alpha; o[jt][mtd][3] *= alpha;
                }
            }
            const float mcur = m_st[jt];
            float psum = 0.f;
            const int prow = w*32 + jt*16 + c;
#pragma unroll
            for (int mt = 0; mt < 4; ++mt) {
                f16x4 hh, ll;
#pragma unroll
                for (int rg = 0; rg < 4; ++rg) {
                    const float pv = __expf(s[jt][mt][rg] - mcur);
                    psum += pv;
                    _Float16 th, tl;
                    split2h(pv, th, tl);
                    hh[rg] = th;
                    ll[rg] = tl;
                }
                *(f16x4*)&PTH[SW(prow, mt*16 + quad*4)] = hh;
                *(f16x4*)&PTL[SW(prow, mt*16 + quad*4)] = ll;
            }
            psum += __shfl_xor(psum, 16);
            psum += __shfl_xor(psum, 32);
            l_st[jt] += psum;
        }
        // wave-private P^T rows: same-wave write->read, no barrier needed

        // ---- PV: O^T[d][q] += V^T P^T (V^T frags shared across jt) ----
#pragma unroll
        for (int kc = 0; kc < 2; ++kc) {
            f16x8 ph[2], pl[2];
#pragma unroll
            for (int jt = 0; jt < 2; ++jt) {
                ph[jt] = *(const f16x8*)&PTH[SW(w*32 + jt*16 + c, kc*32 + quad*8)];
                pl[jt] = *(const f16x8*)&PTL[SW(w*32 + jt*16 + c, kc*32 + quad*8)];
            }
#pragma unroll
            for (int mtd = 0; mtd < 4; ++mtd) {
                f16x8 vh = *(const f16x8*)&VTH[SWV(mtd*16 + c, kc*32 + quad*8)];
                f16x8 vl = *(const f16x8*)&VTL[SWV(mtd*16 + c, kc*32 + quad*8)];
#pragma unroll
                for (int jt = 0; jt < 2; ++jt) {
                    f32x4 v = o[jt][mtd];
                    v = __builtin_amdgcn_mfma_f32_16x16x32_f16(vh, pl[jt], v, 0, 0, 0);
                    v = __builtin_amdgcn_mfma_f32_16x16x32_f16(vl, ph[jt], v, 0, 0, 0);
                    v = __builtin_amdgcn_mfma_f32_16x16x32_f16(vh, ph[jt], v, 0, 0, 0);
                    o[jt][mtd] = v;
                }
            }
        }

        // ---- stage prefetched tile ----
        if (kt < 31) {
            __syncthreads();   // all waves done reading KH/KL/VTH/VTL
#pragma unroll
            for (int i = 0; i < 4; ++i) {
                *(f16x4*)&KH[SW(r0 + i, c0)] = nh[i];
                *(f16x4*)&KL[SW(r0 + i, c0)] = nl[i];
            }
#pragma unroll
            for (int j = 0; j < 4; ++j) {
                *(f16x4*)&VTH[SWV(c0 + j, r0)] = (f16x4){nh[0][j], nh[1][j], nh[2][j], nh[3][j]};
                *(f16x4*)&VTL[SWV(c0 + j, r0)] = (f16x4){nl[0][j], nl[1][j], nl[2][j], nl[3][j]};
            }
            __syncthreads();
        }
    }

    // ---- epilogue: O^T C-layout -> AC rows ----
    const size_t gbase = ac_base(grp);
#pragma unroll
    for (int jt = 0; jt < 2; ++jt) {
        const float inv = 1.0f / l_st[jt];
        const int qrow = qt*128 + w*32 + jt*16 + c;
        float* dst = AC + gbase + ((size_t)((b*nseg + seg)*2048 + qrow)) * 256 + hg*64;
#pragma unroll
        for (int mtd = 0; mtd < 4; ++mtd) {
            float4 v = make_float4(o[jt][mtd][0]*inv, o[jt][mtd][1]*inv,
                                   o[jt][mtd][2]*inv, o[jt][mtd][3]*inv);
            *(float4*)(dst + mtd*16 + quad*4) = v;
        }
    }
}

// ---------------------------------------------------------------------------
// Per-(group,b,head-in-group,d) sums over all positions.
// R14: 448 blocks (4 sub-chunks of 64 positions each, merged by the existing
// atomicAdd) -- the 112-block version used only 44% of CUs at ~2.7 TB/s.
// ---------------------------------------------------------------------------
__global__ __launch_bounds__(256) void sum_kernel(
    const float* __restrict__ AC, float* __restrict__ SUMS) {
    const int sub = blockIdx.x & 3;
    const int bi  = blockIdx.x >> 2;
    int grp, local;
    if (bi < 64)      { grp = 0; local = bi; }
    else if (bi < 96) { grp = 1; local = bi - 64; }
    else              { grp = 2; local = bi - 96; }
    const int chunks = 32 >> grp;
    const int b  = local / chunks;
    const int ch = local - b * chunks;
    const int P  = 8192 >> grp;
    const size_t base = ac_base(grp) + ((size_t)b * P + ch * 256) * 256 + threadIdx.x;
    float acc = 0.f;
    const int p0 = sub * 64;
    for (int p = p0; p < p0 + 64; ++p) acc += AC[base + (size_t)p * 256];
    atomicAdd(&SUMS[((grp << 1) + b) * 256 + threadIdx.x], acc);
}

// ---------------------------------------------------------------------------
// Renormalize + scatter + /3 + LayerNorm, writing OLN as bf16 hi/lo split
// (fuses GEMM5's A-side conversion; values bit-identical to the fp32 path).
// ---------------------------------------------------------------------------
__device__ __forceinline__ float block_reduce_sum(float val, float* sdata) {
    __syncthreads();
#pragma unroll
    for (int o = 32; o > 0; o >>= 1) val += __shfl_down(val, o);
    const int lane = threadIdx.x & 63, wid = threadIdx.x >> 6;
    if (lane == 0) sdata[wid] = val;
    __syncthreads();
    return sdata[0] + sdata[1] + sdata[2] + sdata[3];
}

__global__ __launch_bounds__(256) void renorm_ln_kernel(
    const float* __restrict__ AC, const float* __restrict__ SUMS,
    const float* __restrict__ gamma, const float* __restrict__ beta,
    unsigned short* __restrict__ OLNH, unsigned short* __restrict__ OLNL) {
    __shared__ float sdata[4];
    const int pos = blockIdx.x;
    const int b = pos >> 13;
    const int n = pos & 8191;

    float v[3];
    int dms[3];
#pragma unroll
    for (int jj = 0; jj < 3; ++jj) {
        const int dm = threadIdx.x + (jj << 8);
        dms[jj] = dm;
        const int h = dm >> 6, d = dm & 63;
        const int grp = h >> 2, hg = h & 3;
        const int r = 1 << grp;
        const int p = n & ((2048 << grp) - 1);
        float val = 0.f;
        if ((p & (r - 1)) == grp) {
            const int nseg = 4 >> grp;
            const int seg  = n >> (11 + grp);
            const int j    = (p - grp) >> grp;
            const float s  = SUMS[((grp << 1) + b) * 256 + (hg << 6) + d];
            val = AC[ac_base(grp) + ((size_t)((b*nseg + seg)*2048 + j)) * 256 + (hg << 6) + d]
                  / (3.0f * s);
        }
        v[jj] = val;
    }

    const float tot = block_reduce_sum(v[0] + v[1] + v[2], sdata);
    const float mu  = tot * (1.0f / 768.0f);
    float sq = 0.f;
#pragma unroll
    for (int jj = 0; jj < 3; ++jj) {
        const float d0 = v[jj] - mu;
        sq += d0 * d0;
    }
    const float var  = block_reduce_sum(sq, sdata) * (1.0f / 768.0f);
    const float rstd = rsqrtf(var + 1e-5f);

    unsigned short* dh = OLNH + (size_t)pos * 768;
    unsigned short* dl = OLNL + (size_t)pos * 768;
#pragma unroll
    for (int jj = 0; jj < 3; ++jj) {
        const float val = (v[jj] - mu) * rstd * gamma[dms[jj]] + beta[dms[jj]];
        const unsigned short h = f2bf(val);
        dh[dms[jj]] = h;
        dl[dms[jj]] = f2bf(val - bf2f(h));
    }
}

// ---------------------------------------------------------------------------
extern "C" void kernel_launch(void* const* d_in, const int* in_sizes, int n_in,
                              void* d_out, int out_size, void* d_ws, size_t ws_size,
                              hipStream_t stream) {
    const float* x     = (const float*)d_in[0];
    const float* w_in  = (const float*)d_in[1];
    const float* b_in  = (const float*)d_in[2];
    const float* w_out = (const float*)d_in[3];
    const float* b_out = (const float*)d_in[4];
    const float* gamma = (const float*)d_in[5];
    const float* beta  = (const float*)d_in[6];
    float* out = (float*)d_out;

    float* ws   = (float*)d_ws;
    _Float16* Qh = (_Float16*)ws;                 // fp16 hi, 12.58M elems
    _Float16* Ql = (_Float16*)ws + QL_ELEM_OFF;   // fp16 lo
    float* AC   = ws + AC_OFF;
    float* SUMS = ws + SUMS_OFF;
    // W splits borrow the (currently dead) AC region
    unsigned short* WsplitH = (unsigned short*)(ws + AC_OFF);
    unsigned short* WsplitL = WsplitH + W_ELEMS;
    // OLN bf16 split reuses the Qh/Ql region (dead after attention)
    unsigned short* OLNH = (unsigned short*)ws;
    unsigned short* OLNL = OLNH + QL_ELEM_OFF;

    // 0) pre-split w_in (AC region is dead until attention)
    split_w_kernel<<<576, 256, 0, stream>>>(w_in, WsplitH, WsplitL);
    // 1) Q = x @ w_in.T + b_in, written as fp16 hi/lo split
    gemm_mfma_pre<<<dim3(128, 6), 256, 0, stream>>>(x, nullptr, nullptr,
                                                    WsplitH, WsplitL, b_in,
                                                    nullptr, Qh, Ql);
    // 2) dilated flash attention (exact R7/R11, frozen)
    attn_mfma_kernel<<<896, 256, 0, stream>>>(Qh, Ql, AC);
    // 3) per-(group,b,h,d) position sums (448-way)
    (void)hipMemsetAsync(SUMS, 0, 1536 * sizeof(float), stream);
    sum_kernel<<<448, 256, 0, stream>>>(AC, SUMS);
    // 4) renorm + scatter + /3 + LayerNorm -> OLN bf16 hi/lo split
    renorm_ln_kernel<<<B_ * N_, 256, 0, stream>>>(AC, SUMS, gamma, beta,
                                                  OLNH, OLNL);
    // 5) pre-split w_out (AC is dead after renorm), then
    //    out = OLN @ w_out.T + b_out (fp32 epilogue)
    split_w_kernel<<<576, 256, 0, stream>>>(w_out, WsplitH, WsplitL);
    gemm_mfma_pre<<<dim3(128, 6), 256, 0, stream>>>(nullptr, OLNH, OLNL,
                                                    WsplitH, WsplitL, b_out,
                                                    out, nullptr, nullptr);
}

// Round 15
// 500.385 us; speedup vs baseline: 1.0716x; 1.0082x over previous
//
#include <hip/hip_runtime.h>
#include <hip/hip_bf16.h>
#include <math.h>

// Problem constants
#define B_   2
#define N_   8192
#define DM   768
#define NH   12
#define HD   64

// Workspace layout:
//   Qh (f16) at byte 0           : 12,582,912 f16  (= floats [0, 6291456))
//   Ql (f16) after it            : 12,582,912 f16
//   (OLNh/OLNl bf16 reuse Qh/Ql region after attention)
//   AC  at float 12,582,912, SUMS at float 19,922,944
//   W splits (589824 u16 x2) live in the AC region while it is dead.
#define QL_ELEM_OFF 12582912ull
#define AC_OFF      12582912ull
#define SUMS_OFF    19922944ull
#define W_ELEMS     589824

typedef short bf16x8 __attribute__((ext_vector_type(8)));
typedef _Float16 f16x8 __attribute__((ext_vector_type(8)));
typedef _Float16 f16x4 __attribute__((ext_vector_type(4)));
typedef float f32x4  __attribute__((ext_vector_type(4)));
typedef unsigned short u16x8 __attribute__((ext_vector_type(8)));
typedef unsigned short u16x4 __attribute__((ext_vector_type(4)));

__device__ __forceinline__ size_t ac_base(int grp) {
    return 8388608ull - (8388608ull >> grp);
}

__device__ __forceinline__ unsigned short f2bf(float f) {
    __hip_bfloat16 h = __float2bfloat16(f);
    return __builtin_bit_cast(unsigned short, h);
}
__device__ __forceinline__ float bf2f(unsigned short u) {
    __hip_bfloat16 h = __builtin_bit_cast(__hip_bfloat16, u);
    return __bfloat162float(h);
}
// fp16 RNE split: f ~= hi + lo with |f - hi - lo| <= 2^-22 |f|.
// NOTE (R6 lesson): the hi/lo split is REQUIRED on Q/K, P, and V -- the
// downstream renorm (x / x.sum over ~8192 positions) has cancellation in the
// denominator and amplifies per-element errors by up to ~3e4; dropping any
// lo term (fp16-only, 2^-11) blew absmax to 6.5 vs the 0.1 threshold.
__device__ __forceinline__ void split2h(float f, _Float16& h, _Float16& l) {
    h = (_Float16)f;
    l = (_Float16)(f - (float)h);
}

// XOR-chunk swizzle for 2-byte arrays, pitch 64 elements (128 B row).
// 16B chunks XORed by (row&7): b128 frag reads conflict-free.
#define SW(row, col) ((((row) << 6)) + ((((col) >> 3) ^ ((row) & 7)) << 3) + ((col) & 7))
// V^T variant: also XOR (row>>3). Validated R4/R7: conflict floor 3.67e6
// with this staging (vs 3.3e7 without).
#define SWV(row, col) ((((row) << 6)) + ((((col) >> 3) ^ ((row) & 7) ^ (((row) >> 3) & 7)) << 3) + ((col) & 7))

// ---------------------------------------------------------------------------
// One-shot fp32 -> bf16 hi/lo split for a 768x768 weight matrix.
// ---------------------------------------------------------------------------
__global__ __launch_bounds__(256) void split_w_kernel(
    const float* __restrict__ src, unsigned short* __restrict__ dh,
    unsigned short* __restrict__ dl) {
    const int i = (blockIdx.x * 256 + threadIdx.x) * 4;
    const float4 v = *(const float4*)(src + i);
    const float vv[4] = {v.x, v.y, v.z, v.w};
    u16x4 h, l;
#pragma unroll
    for (int j = 0; j < 4; ++j) {
        h[j] = f2bf(vv[j]);
        l[j] = f2bf(vv[j] - bf2f(h[j]));
    }
    *(u16x4*)(dh + i) = h;
    *(u16x4*)(dl + i) = l;
}

// ---------------------------------------------------------------------------
// Split-bf16 MFMA GEMM (NT). W is ALWAYS pre-split bf16 (WH/WL). A is fp32
// (Af != nullptr -- GEMM1) or pre-split bf16 (Ah/Al -- GEMM5).
// R15: M-tile 128 -> 64 (grid 256x6 = 1536 blocks). LDS 40 -> 30 KB ->
// 5 blocks/CU resident (20 waves/CU vs 12): barrier drains of one block now
// overlap with 4 other blocks' MFMA (m114 mechanism; the GEMMs were
// residency-bound at ~24% util). Per-wave tile 64x32, acc[4][2].
// R14's register prefetch schedule preserved. Arithmetic per output element
// bit-identical (same MFMA sequence, same K order).
// ---------------------------------------------------------------------------
__global__ __launch_bounds__(256) void gemm_mfma_pre(
    const float* __restrict__ Af,
    const unsigned short* __restrict__ Ah, const unsigned short* __restrict__ Al,
    const unsigned short* __restrict__ WH, const unsigned short* __restrict__ WL,
    const float* __restrict__ bias, float* __restrict__ C,
    _Float16* __restrict__ Ch, _Float16* __restrict__ Cl) {
    __shared__ unsigned short AsH[64][40];
    __shared__ unsigned short AsL[64][40];
    __shared__ unsigned short WsH[128][40];
    __shared__ unsigned short WsL[128][40];

    const int t    = threadIdx.x;
    const int lane = t & 63;
    const int wv   = t >> 6;
    const int c    = lane & 15, q = lane >> 4;
    const int nw   = wv * 32;                      // wave's N-offset (4 x 32)
    const int m0   = blockIdx.x * 64, n0 = blockIdx.y * 128;

    const int srA = t >> 2;          // A staging rows 0..63 (4 threads/row)
    const int scA = (t & 3) * 8;     // A staging cols 0,8,16,24
    const int srW = t >> 1;          // W staging rows 0..127
    const int scW = (t & 1) * 16;    // W staging cols 0,16

    const float* ap = Af ? Af + (size_t)(m0 + srA) * DM + scA : nullptr;
    const unsigned short* ahp = Ah ? Ah + (size_t)(m0 + srA) * DM + scA : nullptr;
    const unsigned short* alp = Al ? Al + (size_t)(m0 + srA) * DM + scA : nullptr;
    const unsigned short* whp = WH + (size_t)(n0 + srW) * DM + scW;
    const unsigned short* wlp = WL + (size_t)(n0 + srW) * DM + scW;

    f32x4 acc[4][2];
#pragma unroll
    for (int mi = 0; mi < 4; ++mi)
#pragma unroll
        for (int ni = 0; ni < 2; ++ni) {
            acc[mi][ni][0] = 0.f; acc[mi][ni][1] = 0.f;
            acc[mi][ni][2] = 0.f; acc[mi][ni][3] = 0.f;
        }

    // software-prefetch registers; load K-step 0
    u16x8 wh0, wh1, wl0, wl1;
    float av[8];
    u16x8 ah0, al0;
    wh0 = *(const u16x8*)(whp);
    wh1 = *(const u16x8*)(whp + 8);
    wl0 = *(const u16x8*)(wlp);
    wl1 = *(const u16x8*)(wlp + 8);
    if (Af) {
        *(float4*)&av[0] = *(const float4*)(ap);
        *(float4*)&av[4] = *(const float4*)(ap + 4);
    } else {
        ah0 = *(const u16x8*)(ahp);
        al0 = *(const u16x8*)(alp);
    }

    for (int k0 = 0; k0 < DM; k0 += 32) {
        __syncthreads();   // prior iteration's LDS reads complete
        if (Af) {
#pragma unroll
            for (int i = 0; i < 8; ++i) {
                const float x = av[i];
                const unsigned short xh = f2bf(x);
                AsH[srA][scA + i] = xh;
                AsL[srA][scA + i] = f2bf(x - bf2f(xh));
            }
        } else {
            *(u16x8*)&AsH[srA][scA] = ah0;
            *(u16x8*)&AsL[srA][scA] = al0;
        }
        *(u16x8*)&WsH[srW][scW]     = wh0;
        *(u16x8*)&WsH[srW][scW + 8] = wh1;
        *(u16x8*)&WsL[srW][scW]     = wl0;
        *(u16x8*)&WsL[srW][scW + 8] = wl1;
        __syncthreads();

        // issue next K-step's loads BEFORE the MFMAs (latency hidden)
        const int kn = k0 + 32;
        if (kn < DM) {
            wh0 = *(const u16x8*)(whp + kn);
            wh1 = *(const u16x8*)(whp + kn + 8);
            wl0 = *(const u16x8*)(wlp + kn);
            wl1 = *(const u16x8*)(wlp + kn + 8);
            if (Af) {
                *(float4*)&av[0] = *(const float4*)(ap + kn);
                *(float4*)&av[4] = *(const float4*)(ap + kn + 4);
            } else {
                ah0 = *(const u16x8*)(ahp + kn);
                al0 = *(const u16x8*)(alp + kn);
            }
        }

        bf16x8 fa_h[4], fa_l[4], fb_h[2], fb_l[2];
#pragma unroll
        for (int i = 0; i < 4; ++i) {
            fa_h[i] = *(const bf16x8*)&AsH[i*16 + c][q*8];
            fa_l[i] = *(const bf16x8*)&AsL[i*16 + c][q*8];
        }
#pragma unroll
        for (int j = 0; j < 2; ++j) {
            fb_h[j] = *(const bf16x8*)&WsH[nw + j*16 + c][q*8];
            fb_l[j] = *(const bf16x8*)&WsL[nw + j*16 + c][q*8];
        }
#pragma unroll
        for (int mi = 0; mi < 4; ++mi)
#pragma unroll
            for (int ni = 0; ni < 2; ++ni) {
                f32x4 v = acc[mi][ni];
                v = __builtin_amdgcn_mfma_f32_16x16x32_bf16(fa_h[mi], fb_l[ni], v, 0, 0, 0);
                v = __builtin_amdgcn_mfma_f32_16x16x32_bf16(fa_l[mi], fb_h[ni], v, 0, 0, 0);
                v = __builtin_amdgcn_mfma_f32_16x16x32_bf16(fa_h[mi], fb_h[ni], v, 0, 0, 0);
                acc[mi][ni] = v;
            }
    }

#pragma unroll
    for (int ni = 0; ni < 2; ++ni) {
        const int col = n0 + nw + ni*16 + c;
        const float bv = bias[col];
#pragma unroll
        for (int mi = 0; mi < 4; ++mi)
#pragma unroll
            for (int r = 0; r < 4; ++r) {
                const int row = m0 + mi*16 + q*4 + r;
                const float val = acc[mi][ni][r] + bv;
                if (Ch) {
                    _Float16 hh, ll;
                    split2h(val, hh, ll);
                    Ch[(size_t)row * DM + col] = hh;
                    Cl[(size_t)row * DM + col] = ll;
                } else {
                    C[(size_t)row * DM + col] = val;
                }
            }
    }
}

// ---------------------------------------------------------------------------
// Split-FP16 MFMA flash attention, S^T orientation, 128-query blocks.
// EXACT R7/R11 structure (best proven: 242.9 us). FROZEN: R10 proved not
// HBM-bound; R8/R9 proved 3 blocks/CU spills; R12 proved fused-sum atomics
// cost more than the sum_kernel they replace.
// ---------------------------------------------------------------------------
__global__ __launch_bounds__(256, 2) void attn_mfma_kernel(
    const _Float16* __restrict__ Qh, const _Float16* __restrict__ Ql,
    float* __restrict__ AC) {
    __shared__ __align__(16) _Float16 KH[4096],  KL[4096];   // K row-major [key][d]
    __shared__ __align__(16) _Float16 VTH[4096], VTL[4096];  // K transposed [d][key]
    __shared__ __align__(16) _Float16 PTH[8192], PTL[8192];  // P^T as [q(128)][k(64)]

    const int t    = threadIdx.x;
    const int lane = t & 63;
    const int w    = t >> 6;
    const int c    = lane & 15, quad = lane >> 4;

    // block -> (grp, b, seg, head, q-tile)
    const int bi  = blockIdx.x;
    const int qt  = bi & 15;           // 16 tiles of 128 queries per 2048
    const int bsh = bi >> 4;
    int grp, local;
    if (bsh < 32)      { grp = 0; local = bsh; }
    else if (bsh < 48) { grp = 1; local = bsh - 32; }
    else               { grp = 2; local = bsh - 48; }
    const int nseg = 4 >> grp;
    const int sseg = 2048 << grp;
    const int r    = 1 << grp;
    const int b    = local / (nseg * 4);
    const int rem  = local - b * nseg * 4;
    const int seg  = rem >> 2;
    const int hg   = rem & 3;
    const int head = grp * 4 + hg;

    const size_t row0 = (size_t)(b * N_ + seg * sseg + grp);
    const int hoff = head * HD;

    const int r0 = (t >> 4) * 4;   // staging rows (keys) 0..60
    const int c0 = (t & 15) * 4;   // staging cols (d)    0..60

    // ---- Q B-frags (loop-invariant): queries qt*128 + w*32 + jt*16 + c ----
    f16x8 qfh[2][2], qfl[2][2];   // [jt][kc]
#pragma unroll
    for (int jt = 0; jt < 2; ++jt) {
        const int qrow = qt*128 + w*32 + jt*16 + c;
        const size_t qoff = (row0 + (size_t)qrow * r) * DM + hoff;
#pragma unroll
        for (int kc = 0; kc < 2; ++kc) {
            f16x8 h = *(const f16x8*)(Qh + qoff + kc*32 + quad*8);
            f16x8 l = *(const f16x8*)(Ql + qoff + kc*32 + quad*8);
            qfh[jt][kc] = h * (_Float16)0.125f;   // fold 1/sqrt(64), exact pow2
            qfl[jt][kc] = l * (_Float16)0.125f;
        }
    }

    // ---- stage K-tile 0 ----
    {
        f16x4 hh[4], ll[4];
#pragma unroll
        for (int i = 0; i < 4; ++i) {
            const size_t off = (row0 + (size_t)(r0 + i) * r) * DM + hoff + c0;
            hh[i] = *(const f16x4*)(Qh + off);
            ll[i] = *(const f16x4*)(Ql + off);
        }
#pragma unroll
        for (int i = 0; i < 4; ++i) {
            *(f16x4*)&KH[SW(r0 + i, c0)] = hh[i];
            *(f16x4*)&KL[SW(r0 + i, c0)] = ll[i];
        }
#pragma unroll
        for (int j = 0; j < 4; ++j) {
            *(f16x4*)&VTH[SWV(c0 + j, r0)] = (f16x4){hh[0][j], hh[1][j], hh[2][j], hh[3][j]};
            *(f16x4*)&VTL[SWV(c0 + j, r0)] = (f16x4){ll[0][j], ll[1][j], ll[2][j], ll[3][j]};
        }
    }
    __syncthreads();

    float m_st[2] = {-1e30f, -1e30f};
    float l_st[2] = {0.f, 0.f};
    f32x4 o[2][4];
#pragma unroll
    for (int jt = 0; jt < 2; ++jt)
#pragma unroll
        for (int i = 0; i < 4; ++i) {
            o[jt][i][0] = 0.f; o[jt][i][1] = 0.f;
            o[jt][i][2] = 0.f; o[jt][i][3] = 0.f;
        }

    for (int kt = 0; kt < 32; ++kt) {
        // prefetch next K-tile into registers
        f16x4 nh[4], nl[4];
        if (kt < 31) {
#pragma unroll
            for (int i = 0; i < 4; ++i) {
                const size_t off = (row0 + (size_t)((kt+1)*64 + r0 + i) * r) * DM + hoff + c0;
                nh[i] = *(const f16x4*)(Qh + off);
                nl[i] = *(const f16x4*)(Ql + off);
            }
        }

        // ---- S^T[k][q]: A = K rows (shared across jt), B = Q^T ----
        f32x4 s[2][4];
#pragma unroll
        for (int jt = 0; jt < 2; ++jt)
#pragma unroll
            for (int mt = 0; mt < 4; ++mt) {
                s[jt][mt][0] = 0.f; s[jt][mt][1] = 0.f;
                s[jt][mt][2] = 0.f; s[jt][mt][3] = 0.f;
            }
#pragma unroll
        for (int kc = 0; kc < 2; ++kc)
#pragma unroll
            for (int mt = 0; mt < 4; ++mt) {
                f16x8 ah = *(const f16x8*)&KH[SW(mt*16 + c, kc*32 + quad*8)];
                f16x8 al = *(const f16x8*)&KL[SW(mt*16 + c, kc*32 + quad*8)];
#pragma unroll
                for (int jt = 0; jt < 2; ++jt) {
                    f32x4 v = s[jt][mt];
                    v = __builtin_amdgcn_mfma_f32_16x16x32_f16(ah, qfl[jt][kc], v, 0, 0, 0);
                    v = __builtin_amdgcn_mfma_f32_16x16x32_f16(al, qfh[jt][kc], v, 0, 0, 0);
                    v = __builtin_amdgcn_mfma_f32_16x16x32_f16(ah, qfh[jt][kc], v, 0, 0, 0);
                    s[jt][mt] = v;
                }
            }

        // ---- per-lane online softmax (independent per jt) + P^T write ----
#pragma unroll
        for (int jt = 0; jt < 2; ++jt) {
            float mloc = s[jt][0][0];
#pragma unroll
            for (int mt = 0; mt < 4; ++mt)
#pragma unroll
                for (int rg = 0; rg < 4; ++rg) mloc = fmaxf(mloc, s[jt][mt][rg]);
            mloc = fmaxf(mloc, __shfl_xor(mloc, 16));
            mloc = fmaxf(mloc, __shfl_xor(mloc, 32));
            // wave-uniform skip: when no query's max moved, alpha == 1 exactly
            if (!__all(mloc <= m_st[jt])) {
                const float mnew  = fmaxf(m_st[jt], mloc);
                const float alpha = __expf(m_st[jt] - mnew);
                m_st[jt] = mnew;
                l_st[jt] *= alpha;
#pragma unroll
                for (int mtd = 0; mtd < 4; ++mtd) {
                    o[jt][mtd][0] *= alpha; o[jt][mtd][1] *= alpha;
                    o[jt][mtd][2] *= alpha; o[jt][mtd][3] *= alpha;
                }
            }
            const float mcur = m_st[jt];
            float psum = 0.f;
            const int prow = w*32 + jt*16 + c;
#pragma unroll
            for (int mt = 0; mt < 4; ++mt) {
                f16x4 hh, ll;
#pragma unroll
                for (int rg = 0; rg < 4; ++rg) {
                    const float pv = __expf(s[jt][mt][rg] - mcur);
                    psum += pv;
                    _Float16 th, tl;
                    split2h(pv, th, tl);
                    hh[rg] = th;
                    ll[rg] = tl;
                }
                *(f16x4*)&PTH[SW(prow, mt*16 + quad*4)] = hh;
                *(f16x4*)&PTL[SW(prow, mt*16 + quad*4)] = ll;
            }
            psum += __shfl_xor(psum, 16);
            psum += __shfl_xor(psum, 32);
            l_st[jt] += psum;
        }
        // wave-private P^T rows: same-wave write->read, no barrier needed

        // ---- PV: O^T[d][q] += V^T P^T (V^T frags shared across jt) ----
#pragma unroll
        for (int kc = 0; kc < 2; ++kc) {
            f16x8 ph[2], pl[2];
#pragma unroll
            for (int jt = 0; jt < 2; ++jt) {
                ph[jt] = *(const f16x8*)&PTH[SW(w*32 + jt*16 + c, kc*32 + quad*8)];
                pl[jt] = *(const f16x8*)&PTL[SW(w*32 + jt*16 + c, kc*32 + quad*8)];
            }
#pragma unroll
            for (int mtd = 0; mtd < 4; ++mtd) {
                f16x8 vh = *(const f16x8*)&VTH[SWV(mtd*16 + c, kc*32 + quad*8)];
                f16x8 vl = *(const f16x8*)&VTL[SWV(mtd*16 + c, kc*32 + quad*8)];
#pragma unroll
                for (int jt = 0; jt < 2; ++jt) {
                    f32x4 v = o[jt][mtd];
                    v = __builtin_amdgcn_mfma_f32_16x16x32_f16(vh, pl[jt], v, 0, 0, 0);
                    v = __builtin_amdgcn_mfma_f32_16x16x32_f16(vl, ph[jt], v, 0, 0, 0);
                    v = __builtin_amdgcn_mfma_f32_16x16x32_f16(vh, ph[jt], v, 0, 0, 0);
                    o[jt][mtd] = v;
                }
            }
        }

        // ---- stage prefetched tile ----
        if (kt < 31) {
            __syncthreads();   // all waves done reading KH/KL/VTH/VTL
#pragma unroll
            for (int i = 0; i < 4; ++i) {
                *(f16x4*)&KH[SW(r0 + i, c0)] = nh[i];
                *(f16x4*)&KL[SW(r0 + i, c0)] = nl[i];
            }
#pragma unroll
            for (int j = 0; j < 4; ++j) {
                *(f16x4*)&VTH[SWV(c0 + j, r0)] = (f16x4){nh[0][j], nh[1][j], nh[2][j], nh[3][j]};
                *(f16x4*)&VTL[SWV(c0 + j, r0)] = (f16x4){nl[0][j], nl[1][j], nl[2][j], nl[3][j]};
            }
            __syncthreads();
        }
    }

    // ---- epilogue: O^T C-layout -> AC rows ----
    const size_t gbase = ac_base(grp);
#pragma unroll
    for (int jt = 0; jt < 2; ++jt) {
        const float inv = 1.0f / l_st[jt];
        const int qrow = qt*128 + w*32 + jt*16 + c;
        float* dst = AC + gbase + ((size_t)((b*nseg + seg)*2048 + qrow)) * 256 + hg*64;
#pragma unroll
        for (int mtd = 0; mtd < 4; ++mtd) {
            float4 v = make_float4(o[jt][mtd][0]*inv, o[jt][mtd][1]*inv,
                                   o[jt][mtd][2]*inv, o[jt][mtd][3]*inv);
            *(float4*)(dst + mtd*16 + quad*4) = v;
        }
    }
}

// ---------------------------------------------------------------------------
// Per-(group,b,head-in-group,d) sums over all positions. (R14: 448-way)
// ---------------------------------------------------------------------------
__global__ __launch_bounds__(256) void sum_kernel(
    const float* __restrict__ AC, float* __restrict__ SUMS) {
    const int sub = blockIdx.x & 3;
    const int bi  = blockIdx.x >> 2;
    int grp, local;
    if (bi < 64)      { grp = 0; local = bi; }
    else if (bi < 96) { grp = 1; local = bi - 64; }
    else              { grp = 2; local = bi - 96; }
    const int chunks = 32 >> grp;
    const int b  = local / chunks;
    const int ch = local - b * chunks;
    const int P  = 8192 >> grp;
    const size_t base = ac_base(grp) + ((size_t)b * P + ch * 256) * 256 + threadIdx.x;
    float acc = 0.f;
    const int p0 = sub * 64;
    for (int p = p0; p < p0 + 64; ++p) acc += AC[base + (size_t)p * 256];
    atomicAdd(&SUMS[((grp << 1) + b) * 256 + threadIdx.x], acc);
}

// ---------------------------------------------------------------------------
// Renormalize + scatter + /3 + LayerNorm, writing OLN as bf16 hi/lo split
// (fuses GEMM5's A-side conversion; values bit-identical to the fp32 path).
// ---------------------------------------------------------------------------
__device__ __forceinline__ float block_reduce_sum(float val, float* sdata) {
    __syncthreads();
#pragma unroll
    for (int o = 32; o > 0; o >>= 1) val += __shfl_down(val, o);
    const int lane = threadIdx.x & 63, wid = threadIdx.x >> 6;
    if (lane == 0) sdata[wid] = val;
    __syncthreads();
    return sdata[0] + sdata[1] + sdata[2] + sdata[3];
}

__global__ __launch_bounds__(256) void renorm_ln_kernel(
    const float* __restrict__ AC, const float* __restrict__ SUMS,
    const float* __restrict__ gamma, const float* __restrict__ beta,
    unsigned short* __restrict__ OLNH, unsigned short* __restrict__ OLNL) {
    __shared__ float sdata[4];
    const int pos = blockIdx.x;
    const int b = pos >> 13;
    const int n = pos & 8191;

    float v[3];
    int dms[3];
#pragma unroll
    for (int jj = 0; jj < 3; ++jj) {
        const int dm = threadIdx.x + (jj << 8);
        dms[jj] = dm;
        const int h = dm >> 6, d = dm & 63;
        const int grp = h >> 2, hg = h & 3;
        const int r = 1 << grp;
        const int p = n & ((2048 << grp) - 1);
        float val = 0.f;
        if ((p & (r - 1)) == grp) {
            const int nseg = 4 >> grp;
            const int seg  = n >> (11 + grp);
            const int j    = (p - grp) >> grp;
            const float s  = SUMS[((grp << 1) + b) * 256 + (hg << 6) + d];
            val = AC[ac_base(grp) + ((size_t)((b*nseg + seg)*2048 + j)) * 256 + (hg << 6) + d]
                  / (3.0f * s);
        }
        v[jj] = val;
    }

    const float tot = block_reduce_sum(v[0] + v[1] + v[2], sdata);
    const float mu  = tot * (1.0f / 768.0f);
    float sq = 0.f;
#pragma unroll
    for (int jj = 0; jj < 3; ++jj) {
        const float d0 = v[jj] - mu;
        sq += d0 * d0;
    }
    const float var  = block_reduce_sum(sq, sdata) * (1.0f / 768.0f);
    const float rstd = rsqrtf(var + 1e-5f);

    unsigned short* dh = OLNH + (size_t)pos * 768;
    unsigned short* dl = OLNL + (size_t)pos * 768;
#pragma unroll
    for (int jj = 0; jj < 3; ++jj) {
        const float val = (v[jj] - mu) * rstd * gamma[dms[jj]] + beta[dms[jj]];
        const unsigned short h = f2bf(val);
        dh[dms[jj]] = h;
        dl[dms[jj]] = f2bf(val - bf2f(h));
    }
}

// ---------------------------------------------------------------------------
extern "C" void kernel_launch(void* const* d_in, const int* in_sizes, int n_in,
                              void* d_out, int out_size, void* d_ws, size_t ws_size,
                              hipStream_t stream) {
    const float* x     = (const float*)d_in[0];
    const float* w_in  = (const float*)d_in[1];
    const float* b_in  = (const float*)d_in[2];
    const float* w_out = (const float*)d_in[3];
    const float* b_out = (const float*)d_in[4];
    const float* gamma = (const float*)d_in[5];
    const float* beta  = (const float*)d_in[6];
    float* out = (float*)d_out;

    float* ws   = (float*)d_ws;
    _Float16* Qh = (_Float16*)ws;                 // fp16 hi, 12.58M elems
    _Float16* Ql = (_Float16*)ws + QL_ELEM_OFF;   // fp16 lo
    float* AC   = ws + AC_OFF;
    float* SUMS = ws + SUMS_OFF;
    // W splits borrow the (currently dead) AC region
    unsigned short* WsplitH = (unsigned short*)(ws + AC_OFF);
    unsigned short* WsplitL = WsplitH + W_ELEMS;
    // OLN bf16 split reuses the Qh/Ql region (dead after attention)
    unsigned short* OLNH = (unsigned short*)ws;
    unsigned short* OLNL = OLNH + QL_ELEM_OFF;

    // 0) pre-split w_in (AC region is dead until attention)
    split_w_kernel<<<576, 256, 0, stream>>>(w_in, WsplitH, WsplitL);
    // 1) Q = x @ w_in.T + b_in, written as fp16 hi/lo split
    gemm_mfma_pre<<<dim3(256, 6), 256, 0, stream>>>(x, nullptr, nullptr,
                                                    WsplitH, WsplitL, b_in,
                                                    nullptr, Qh, Ql);
    // 2) dilated flash attention (exact R7/R11, frozen)
    attn_mfma_kernel<<<896, 256, 0, stream>>>(Qh, Ql, AC);
    // 3) per-(group,b,h,d) position sums (448-way)
    (void)hipMemsetAsync(SUMS, 0, 1536 * sizeof(float), stream);
    sum_kernel<<<448, 256, 0, stream>>>(AC, SUMS);
    // 4) renorm + scatter + /3 + LayerNorm -> OLN bf16 hi/lo split
    renorm_ln_kernel<<<B_ * N_, 256, 0, stream>>>(AC, SUMS, gamma, beta,
                                                  OLNH, OLNL);
    // 5) pre-split w_out (AC is dead after renorm), then
    //    out = OLN @ w_out.T + b_out (fp32 epilogue)
    split_w_kernel<<<576, 256, 0, stream>>>(w_out, WsplitH, WsplitL);
    gemm_mfma_pre<<<dim3(256, 6), 256, 0, stream>>>(nullptr, OLNH, OLNL,
                                                    WsplitH, WsplitL, b_out,
                                                    out, nullptr, nullptr);
}